// Round 9
// baseline (522.414 us; speedup 1.0000x reference)
//
#include <hip/hip_runtime.h>
#include <hip/hip_bf16.h>
#include <cstdint>

using bf16 = __hip_bfloat16;
typedef __attribute__((ext_vector_type(8))) short bf16x8v;
typedef __attribute__((ext_vector_type(4))) float f32x4v;

__device__ __forceinline__ void gload_lds16(const void* g, void* l) {
  __builtin_amdgcn_global_load_lds(
      (const __attribute__((address_space(1))) void*)g,
      (__attribute__((address_space(3))) void*)l, 16, 0, 0);
}

__device__ __forceinline__ unsigned short f2bu(float x) {
  union { __hip_bfloat16 h; unsigned short u; } cv;
  cv.h = __float2bfloat16(x);
  return cv.u;
}

__device__ __forceinline__ bf16x8v cvt8(const f32x4v lo, const f32x4v hi) {
  bf16x8v t;
  t[0] = (short)f2bu(lo[0]); t[1] = (short)f2bu(lo[1]);
  t[2] = (short)f2bu(lo[2]); t[3] = (short)f2bu(lo[3]);
  t[4] = (short)f2bu(hi[0]); t[5] = (short)f2bu(hi[1]);
  t[6] = (short)f2bu(hi[2]); t[7] = (short)f2bu(hi[3]);
  return t;
}

// ---------------------------------------------------------------------------
// Generic batched "bt" GEMM (128x128 tile, 4 waves, 16x16x32 MFMA core).
// C = scale * A * B^T. Proven best structure (R7: final GEMM ~170us, 0 LDS
// conflicts). NOTE: 32x32x16 core was tried (R8) -> 1.7e7 bank conflicts,
// +17us; the XOR-slot swizzle is only conflict-free for the 16-row x 4-kgroup
// read pattern. launch_bounds(256,5): VGPR 60<=64 allows 8 waves/SIMD; LDS
// 32KB -> exactly 5 blocks/CU (160KB). One extra co-resident block adds
// implicit overlap across the per-tile barrier drain.
// ---------------------------------------------------------------------------
struct GemmP {
  const void* A; const void* B; const void* A2; const void* B2; void* C;
  int K, lda, ldb, ldc, tilesN, swz;
  int d0, d1, d2;
  long long sA0, sA1, sA2, sA3;
  long long sB0, sB1, sB2, sB3;
  long long sC0, sC1, sC2, sC3;
  long long zA, zB, zC;
  float scale;
};

template<int OUT_F32, int AF32, int BF32>
__global__ __launch_bounds__(256, 5)
void gemm_bt(GemmP p)
{
  constexpr int EA = AF32 ? 4 : 2;
  constexpr int EB = BF32 ? 4 : 2;
  constexpr int ABYTES = 128 * 64 * EA;
  constexpr int BBYTES = 128 * 64 * EB;
  constexpr int SEGA = ABYTES / 4096;
  constexpr int SEGB = BBYTES / 4096;
  __shared__ __attribute__((aligned(1024))) char smem[ABYTES + BBYTES];
  const int tid  = threadIdx.x;
  const int lane = tid & 63;
  const int wid  = tid >> 6;

  int bx = blockIdx.x;
  if (p.swz) {
    const int nx = gridDim.x;
    const int q = nx >> 3, r = nx & 7;
    const int xcd = bx & 7, loc = bx >> 3;
    bx = (xcd < r ? xcd * (q + 1) : r * (q + 1) + (xcd - r) * q) + loc;
  }
  const int tn = bx % p.tilesN;
  const int tm = bx / p.tilesN;
  int idx = blockIdx.y;
  const int i0 = idx % p.d0; idx /= p.d0;
  const int i1 = idx % p.d1; idx /= p.d1;
  const int i2 = idx % p.d2;
  const int i3 = idx / p.d2;

  const char* Abase = (const char*)((p.A2 && i2) ? p.A2 : p.A);
  const char* Bbase = (const char*)((p.B2 && i2) ? p.B2 : p.B);
  const long long offA = (long long)i0*p.sA0 + (long long)i1*p.sA1 +
                         (long long)i2*p.sA2 + (long long)i3*p.sA3 +
                         (long long)blockIdx.z*p.zA;
  const long long offB = (long long)i0*p.sB0 + (long long)i1*p.sB1 +
                         (long long)i2*p.sB2 + (long long)i3*p.sB3 +
                         (long long)blockIdx.z*p.zB;
  const char* Am = Abase + offA * EA;
  const char* Bm = Bbase + offB * EB;
  const int bm = tm * 128, bn = tn * 128;

  const char* asrc[SEGA]; int aseg[SEGA];
  #pragma unroll
  for (int r = 0; r < SEGA; ++r) {
    const int oseg = (wid * SEGA + r) * 1024;
    const int o = oseg + lane * 16;
    int row, srcoff;
    if constexpr (AF32) { row = o >> 8; const int s = (o >> 4) & 15; srcoff = (s ^ (row & 15)) * 4; }
    else               { row = o >> 7; const int s = (o >> 4) & 7;  srcoff = (s ^ (row & 7)) * 8;  }
    aseg[r] = oseg;
    asrc[r] = Am + ((long long)(bm + row) * p.lda + srcoff) * EA;
  }
  const char* bsrc[SEGB]; int bseg[SEGB];
  #pragma unroll
  for (int r = 0; r < SEGB; ++r) {
    const int oseg = (wid * SEGB + r) * 1024;
    const int o = oseg + lane * 16;
    int row, srcoff;
    if constexpr (BF32) { row = o >> 8; const int s = (o >> 4) & 15; srcoff = (s ^ (row & 15)) * 4; }
    else               { row = o >> 7; const int s = (o >> 4) & 7;  srcoff = (s ^ (row & 7)) * 8;  }
    bseg[r] = oseg;
    bsrc[r] = Bm + ((long long)(bn + row) * p.ldb + srcoff) * EB;
  }

  f32x4v acc[4][4];
  #pragma unroll
  for (int i = 0; i < 4; ++i)
    #pragma unroll
    for (int j = 0; j < 4; ++j) acc[i][j] = (f32x4v){0.f, 0.f, 0.f, 0.f};

  const int wr = wid >> 1, wc = wid & 1;
  const int fr_a = wr * 64 + (lane & 15);
  const int fr_b = wc * 64 + (lane & 15);
  const int fch  = lane >> 4;

  const int nK = p.K / 64;
  for (int kt = 0; kt < nK; ++kt) {
    #pragma unroll
    for (int r = 0; r < SEGA; ++r) { gload_lds16(asrc[r], smem + aseg[r]); asrc[r] += 64 * EA; }
    #pragma unroll
    for (int r = 0; r < SEGB; ++r) { gload_lds16(bsrc[r], smem + ABYTES + bseg[r]); bsrc[r] += 64 * EB; }
    __syncthreads();
    #pragma unroll
    for (int kk = 0; kk < 2; ++kk) {
      bf16x8v a[4], b[4];
      #pragma unroll
      for (int mi = 0; mi < 4; ++mi) {
        const int row = fr_a + mi * 16;
        if constexpr (AF32) {
          const int c2 = (fch + kk * 4) * 2;
          const f32x4v lo = *(const f32x4v*)(smem + row * 256 + ((c2 ^ (row & 15)) << 4));
          const f32x4v hi = *(const f32x4v*)(smem + row * 256 + (((c2 + 1) ^ (row & 15)) << 4));
          a[mi] = cvt8(lo, hi);
        } else {
          a[mi] = *(const bf16x8v*)(smem + row * 128 + (((fch + kk * 4) ^ (row & 7)) << 4));
        }
      }
      #pragma unroll
      for (int ni = 0; ni < 4; ++ni) {
        const int row = fr_b + ni * 16;
        if constexpr (BF32) {
          const int c2 = (fch + kk * 4) * 2;
          const f32x4v lo = *(const f32x4v*)(smem + ABYTES + row * 256 + ((c2 ^ (row & 15)) << 4));
          const f32x4v hi = *(const f32x4v*)(smem + ABYTES + row * 256 + (((c2 + 1) ^ (row & 15)) << 4));
          b[ni] = cvt8(lo, hi);
        } else {
          b[ni] = *(const bf16x8v*)(smem + ABYTES + row * 128 + (((fch + kk * 4) ^ (row & 7)) << 4));
        }
      }
      #pragma unroll
      for (int mi = 0; mi < 4; ++mi)
        #pragma unroll
        for (int ni = 0; ni < 4; ++ni)
          acc[mi][ni] = __builtin_amdgcn_mfma_f32_16x16x32_bf16(a[mi], b[ni], acc[mi][ni], 0, 0, 0);
    }
    __syncthreads();
  }

  const long long coff = (long long)i0*p.sC0 + (long long)i1*p.sC1 +
                         (long long)i2*p.sC2 + (long long)i3*p.sC3 +
                         (long long)blockIdx.z*p.zC;
  const int col0 = bn + wc * 64 + (lane & 15);
  const int row0 = bm + wr * 64 + ((lane >> 4) << 2);
  if (OUT_F32) {
    float* Cp = (float*)p.C + coff;
    #pragma unroll
    for (int mi = 0; mi < 4; ++mi)
      #pragma unroll
      for (int ni = 0; ni < 4; ++ni)
        #pragma unroll
        for (int j = 0; j < 4; ++j)
          Cp[(size_t)(row0 + mi*16 + j) * p.ldc + (col0 + ni*16)] = acc[mi][ni][j] * p.scale;
  } else {
    bf16* Cp = (bf16*)p.C + coff;
    #pragma unroll
    for (int mi = 0; mi < 4; ++mi)
      #pragma unroll
      for (int ni = 0; ni < 4; ++ni)
        #pragma unroll
        for (int j = 0; j < 4; ++j)
          Cp[(size_t)(row0 + mi*16 + j) * p.ldc + (col0 + ni*16)] =
              __float2bfloat16(acc[mi][ni][j] * p.scale);
  }
}

// ---------------------------------------------------------------------------
// 256x256-tile, 8-wave, PHASED double-buffered GEMM (scores GEMM only).
// ---------------------------------------------------------------------------
struct G256P {
  const bf16* A; const bf16* B; void* C;
  int lda, ldb, ldc, nt, tilesN, swz;
  int d0, d1, d2;
  long long sA0, sA1, sA2, sA3;
  long long sB0, sB1, sB2, sB3;
  long long sC0, sC1, sC2, sC3;
  long long zA, zB, zC;
  float scale;
};

template<int OUT_F32>
__global__ __launch_bounds__(512, 1)
void gemm256_bt(G256P p)
{
  __shared__ __attribute__((aligned(1024))) char smem[131072];
  const int tid = threadIdx.x, lane = tid & 63, wid = tid >> 6;

  int bx = blockIdx.x;
  if (p.swz) {
    const int nx = gridDim.x;
    const int q = nx >> 3, r = nx & 7;
    const int xcd = bx & 7, loc = bx >> 3;
    bx = (xcd < r ? xcd * (q + 1) : r * (q + 1) + (xcd - r) * q) + loc;
  }
  const int tn = bx % p.tilesN, tm = bx / p.tilesN;
  int idx = blockIdx.y;
  const int i0 = idx % p.d0; idx /= p.d0;
  const int i1 = idx % p.d1; idx /= p.d1;
  const int i2 = idx % p.d2;
  const int i3 = idx / p.d2;

  const bf16* Am = p.A + ((long long)i0*p.sA0 + (long long)i1*p.sA1 +
                          (long long)i2*p.sA2 + (long long)i3*p.sA3 +
                          (long long)blockIdx.z*p.zA) + (long long)tm * 256 * p.lda;
  const bf16* Bm = p.B + ((long long)i0*p.sB0 + (long long)i1*p.sB1 +
                          (long long)i2*p.sB2 + (long long)i3*p.sB3 +
                          (long long)blockIdx.z*p.zB) + (long long)tn * 256 * p.ldb;

  int arow[2][2]; int ach[2][2];
  #pragma unroll
  for (int hh = 0; hh < 2; ++hh)
    #pragma unroll
    for (int l = 0; l < 2; ++l) {
      const int seg = hh * 16 + wid * 2 + l;
      const int o = seg * 1024 + lane * 16;
      const int row = o >> 7;
      arow[hh][l] = row;
      ach[hh][l] = ((o >> 4) & 7) ^ (row & 7);
    }

  auto stageA = [&](int kt, int hh, int buf) {
    #pragma unroll
    for (int l = 0; l < 2; ++l) {
      const int seg = hh * 16 + wid * 2 + l;
      gload_lds16(Am + (long long)arow[hh][l] * p.lda + ach[hh][l] * 8 + kt * 64,
                  smem + buf * 32768 + seg * 1024);
    }
  };
  auto stageB = [&](int kt, int hh, int buf) {
    #pragma unroll
    for (int l = 0; l < 2; ++l) {
      const int seg = hh * 16 + wid * 2 + l;
      gload_lds16(Bm + (long long)arow[hh][l] * p.ldb + ach[hh][l] * 8 + kt * 64,
                  smem + 65536 + buf * 32768 + seg * 1024);
    }
  };

  stageA(0, 0, 0); stageA(0, 1, 0);
  stageB(0, 0, 0); stageB(0, 1, 0);
  if (p.nt > 1) { stageB(1, 0, 1); stageB(1, 1, 1); }
  asm volatile("s_waitcnt vmcnt(0)" ::: "memory");
  __builtin_amdgcn_s_barrier();

  f32x4v acc[8][4];
  #pragma unroll
  for (int i = 0; i < 8; ++i)
    #pragma unroll
    for (int j = 0; j < 4; ++j) acc[i][j] = (f32x4v){0.f, 0.f, 0.f, 0.f};

  const int wr = wid >> 2, wc = wid & 3;
  const int rA = wr * 128 + (lane & 15);
  const int rB = wc * 64 + (lane & 15);
  const int fch = lane >> 4;

  bf16x8v bfr[2][4];

  for (int t = 0; t < p.nt; ++t) {
    const int pb = t & 1;
    const char* Ab = smem + pb * 32768;
    const char* Bb = smem + 65536 + pb * 32768;

    #pragma unroll
    for (int q = 0; q < 4; ++q) {
      if (q == 0) {
        #pragma unroll
        for (int kk = 0; kk < 2; ++kk)
          #pragma unroll
          for (int ni = 0; ni < 4; ++ni) {
            const int row = rB + ni * 16;
            bfr[kk][ni] = *(const bf16x8v*)(Bb + row * 128 +
                                            (((fch + kk * 4) ^ (row & 7)) << 4));
          }
      }
      bf16x8v afr[2][2];
      #pragma unroll
      for (int kk = 0; kk < 2; ++kk)
        #pragma unroll
        for (int s = 0; s < 2; ++s) {
          const int row = rA + (q * 2 + s) * 16;
          afr[kk][s] = *(const bf16x8v*)(Ab + row * 128 +
                                         (((fch + kk * 4) ^ (row & 7)) << 4));
        }
      if (q == 0 && t + 1 < p.nt) stageA(t + 1, 0, pb ^ 1);
      if (q == 1 && t + 1 < p.nt) stageA(t + 1, 1, pb ^ 1);
      if (q == 2 && t + 2 < p.nt) stageB(t + 2, 0, pb);
      if (q == 3) {
        if (t + 2 < p.nt) {
          stageB(t + 2, 1, pb);
          asm volatile("s_waitcnt vmcnt(4)" ::: "memory");
        } else {
          asm volatile("s_waitcnt vmcnt(0)" ::: "memory");
        }
      }
      __builtin_amdgcn_s_barrier();
      asm volatile("s_waitcnt lgkmcnt(0)" ::: "memory");
      __builtin_amdgcn_sched_barrier(0);
      __builtin_amdgcn_s_setprio(1);
      #pragma unroll
      for (int kk = 0; kk < 2; ++kk)
        #pragma unroll
        for (int s = 0; s < 2; ++s)
          #pragma unroll
          for (int ni = 0; ni < 4; ++ni)
            acc[q * 2 + s][ni] = __builtin_amdgcn_mfma_f32_16x16x32_bf16(
                afr[kk][s], bfr[kk][ni], acc[q * 2 + s][ni], 0, 0, 0);
      __builtin_amdgcn_s_setprio(0);
      __builtin_amdgcn_sched_barrier(0);
      __builtin_amdgcn_s_barrier();
    }
  }

  const long long coff = (long long)i0*p.sC0 + (long long)i1*p.sC1 +
                         (long long)i2*p.sC2 + (long long)i3*p.sC3 +
                         (long long)blockIdx.z*p.zC;
  const int col0 = tn * 256 + wc * 64 + (lane & 15);
  const int row0 = tm * 256 + wr * 128 + ((lane >> 4) << 2);
  if (OUT_F32) {
    float* Cp = (float*)p.C + coff;
    #pragma unroll
    for (int mi = 0; mi < 8; ++mi)
      #pragma unroll
      for (int ni = 0; ni < 4; ++ni)
        #pragma unroll
        for (int j = 0; j < 4; ++j)
          Cp[(size_t)(row0 + mi*16 + j) * p.ldc + (col0 + ni*16)] = acc[mi][ni][j] * p.scale;
  } else {
    bf16* Cp = (bf16*)p.C + coff;
    #pragma unroll
    for (int mi = 0; mi < 8; ++mi)
      #pragma unroll
      for (int ni = 0; ni < 4; ++ni)
        #pragma unroll
        for (int j = 0; j < 4; ++j)
          Cp[(size_t)(row0 + mi*16 + j) * p.ldc + (col0 + ni*16)] =
              __float2bfloat16(acc[mi][ni][j] * p.scale);
  }
}

// ---------------------------------------------------------------------------
// Fused K+V projection (shared X tile).
// ---------------------------------------------------------------------------
struct KVP {
  const float* X0; const float* X1;
  const bf16* Wk; const bf16* Wv;
  bf16* KT; bf16* Vc;
};

__global__ __launch_bounds__(256, 2)
void kv_fused(KVP p)
{
  __shared__ __attribute__((aligned(1024))) char smem[65536];
  const int tid = threadIdx.x, lane = tid & 63, wid = tid >> 6;
  const int jt = blockIdx.x & 1, nt = blockIdx.x >> 1;
  int idx = blockIdx.y;
  const int h = idx & 3; idx >>= 2;
  const int b = idx & 3; idx >>= 2;
  const int vi = idx;
  const float* X = (vi ? p.X1 : p.X0) + (size_t)b * 4194304 + (size_t)h * 256;
  const bf16* Wk = p.Wk + (size_t)h * 65536;
  const bf16* Wv = p.Wv + (size_t)h * 65536;
  const int n0 = nt * 128, j0 = jt * 128;

  const float* xsrc[8];
  #pragma unroll
  for (int r = 0; r < 8; ++r) {
    const int o = (wid * 8 + r) * 1024 + lane * 16;
    const int row = o >> 8, s = (o >> 4) & 15;
    xsrc[r] = X + (size_t)(n0 + row) * 1024 + (s ^ (row & 15)) * 4;
  }
  const bf16 *wksrc[4], *wvsrc[4];
  #pragma unroll
  for (int r = 0; r < 4; ++r) {
    const int o = (wid * 4 + r) * 1024 + lane * 16;
    const int row = o >> 7, s = (o >> 4) & 7;
    wksrc[r] = Wk + (size_t)(j0 + row) * 256 + (s ^ (row & 7)) * 8;
    wvsrc[r] = Wv + (size_t)(j0 + row) * 256 + (s ^ (row & 7)) * 8;
  }

  f32x4v accK[4][4], accV[4][4];
  #pragma unroll
  for (int i = 0; i < 4; ++i)
    #pragma unroll
    for (int j = 0; j < 4; ++j) {
      accK[i][j] = (f32x4v){0.f, 0.f, 0.f, 0.f};
      accV[i][j] = (f32x4v){0.f, 0.f, 0.f, 0.f};
    }

  const int wr = wid >> 1, wc = wid & 1;
  const int frW = wr * 64 + (lane & 15);
  const int frX = wc * 64 + (lane & 15);
  const int fch = lane >> 4;

  for (int kt = 0; kt < 4; ++kt) {
    #pragma unroll
    for (int r = 0; r < 8; ++r) { gload_lds16(xsrc[r], smem + (wid * 8 + r) * 1024); xsrc[r] += 64; }
    #pragma unroll
    for (int r = 0; r < 4; ++r) {
      gload_lds16(wksrc[r], smem + 32768 + (wid * 4 + r) * 1024); wksrc[r] += 64;
      gload_lds16(wvsrc[r], smem + 49152 + (wid * 4 + r) * 1024); wvsrc[r] += 64;
    }
    __syncthreads();
    #pragma unroll
    for (int kk = 0; kk < 2; ++kk) {
      bf16x8v wk[4], wv[4], x[4];
      #pragma unroll
      for (int mi = 0; mi < 4; ++mi) {
        const int row = frW + mi * 16;
        const int byo = row * 128 + (((fch + kk * 4) ^ (row & 7)) << 4);
        wk[mi] = *(const bf16x8v*)(smem + 32768 + byo);
        wv[mi] = *(const bf16x8v*)(smem + 49152 + byo);
      }
      #pragma unroll
      for (int ni = 0; ni < 4; ++ni) {
        const int row = frX + ni * 16;
        const int c2 = (fch + kk * 4) * 2;
        const f32x4v lo = *(const f32x4v*)(smem + row * 256 + ((c2 ^ (row & 15)) << 4));
        const f32x4v hi = *(const f32x4v*)(smem + row * 256 + (((c2 + 1) ^ (row & 15)) << 4));
        x[ni] = cvt8(lo, hi);
      }
      #pragma unroll
      for (int mi = 0; mi < 4; ++mi)
        #pragma unroll
        for (int ni = 0; ni < 4; ++ni) {
          accK[mi][ni] = __builtin_amdgcn_mfma_f32_16x16x32_bf16(wk[mi], x[ni], accK[mi][ni], 0, 0, 0);
          accV[ni][mi] = __builtin_amdgcn_mfma_f32_16x16x32_bf16(x[ni], wv[mi], accV[ni][mi], 0, 0, 0);
        }
    }
    __syncthreads();
  }

  const size_t kbase = (size_t)vi * 16777216 + (size_t)b * 4194304 + (size_t)h * 1048576;
  const size_t vbase = (size_t)vi * 16777216 + (size_t)b * 4194304;
  bf16* Kp = p.KT + kbase;
  bf16* Vp = p.Vc + vbase;
  const int rW = ((lane >> 4) << 2);
  #pragma unroll
  for (int mi = 0; mi < 4; ++mi)
    #pragma unroll
    for (int ni = 0; ni < 4; ++ni)
      #pragma unroll
      for (int j = 0; j < 4; ++j) {
        const int jrow = j0 + wr * 64 + mi * 16 + rW + j;
        const int ncol = n0 + wc * 64 + ni * 16 + (lane & 15);
        Kp[(size_t)jrow * 4096 + ncol] = __float2bfloat16(accK[mi][ni][j]);
        const int nrow = n0 + wc * 64 + ni * 16 + rW + j;
        const int jcol = j0 + wr * 64 + mi * 16 + (lane & 15);
        Vp[(size_t)nrow * 1024 + h * 256 + jcol] = __float2bfloat16(accV[ni][mi][j]);
      }
}

// ---------------------------------------------------------------------------
// weight conversions
// ---------------------------------------------------------------------------
__global__ void cvt3_f32_bf16(const float* __restrict__ a0, const float* __restrict__ a1,
                              const float* __restrict__ a2,
                              unsigned short* __restrict__ out, long long ostride, int n4) {
  const int i = blockIdx.x * 256 + threadIdx.x;
  if (i >= n4) return;
  const float* src = (blockIdx.y == 0) ? a0 : (blockIdx.y == 1) ? a1 : a2;
  const float4 v = ((const float4*)src)[i];
  ushort4 o;
  o.x = f2bu(v.x); o.y = f2bu(v.y); o.z = f2bu(v.z); o.w = f2bu(v.w);
  ((ushort4*)(out + (size_t)blockIdx.y * ostride))[i] = o;
}

__global__ void wpre_kernel(const float* __restrict__ Wout, const float* __restrict__ Woutd,
                            bf16* __restrict__ Wpre) {
  const int w = blockIdx.y;
  const int flat = blockIdx.x * 256 + threadIdx.x;
  const float* Wsrc = w ? Woutd : Wout;
  const int o  = flat >> 10;
  const int c2 = flat & 1023;
  const int h  = c2 >> 8;
  const int i  = c2 & 255;
  Wpre[(size_t)w * 1048576 + flat] = __float2bfloat16(Wsrc[o * 1024 + i * 4 + h]);
}

// ---------------------------------------------------------------------------
// Stage 1: per quarter-matrix sum/sumsq of z-summed scores (deterministic).
// ---------------------------------------------------------------------------
__global__ __launch_bounds__(256)
void stats_quarter(const float* __restrict__ sp, float* __restrict__ st) {
  const int m = blockIdx.x >> 2, q = blockIdx.x & 3;
  const size_t PS = 4194304;
  const float* s = sp + (size_t)m * 65536 + (size_t)q * 16384;
  const int tid = threadIdx.x, lane = tid & 63, w = tid >> 6;

  float sum = 0.f, sq = 0.f;
  for (int i = tid; i < 4096; i += 256) {
    const float4 a = ((const float4*)s)[i];
    const float4 b = ((const float4*)(s + PS))[i];
    const float4 c = ((const float4*)(s + 2 * PS))[i];
    const float4 d = ((const float4*)(s + 3 * PS))[i];
    const float x0 = (a.x + b.x) + (c.x + d.x);
    const float x1 = (a.y + b.y) + (c.y + d.y);
    const float x2 = (a.z + b.z) + (c.z + d.z);
    const float x3 = (a.w + b.w) + (c.w + d.w);
    sum += (x0 + x1) + (x2 + x3);
    sq  += (x0 * x0 + x1 * x1) + (x2 * x2 + x3 * x3);
  }
  #pragma unroll
  for (int o = 32; o; o >>= 1) { sum += __shfl_xor(sum, o); sq += __shfl_xor(sq, o); }
  __shared__ float red[8];
  if (lane == 0) { red[w] = sum; red[4 + w] = sq; }
  __syncthreads();
  if (tid == 0) {
    st[blockIdx.x * 2]     = (red[0] + red[1]) + (red[2] + red[3]);
    st[blockIdx.x * 2 + 1] = (red[4] + red[5]) + (red[6] + red[7]);
  }
}

// ---------------------------------------------------------------------------
// Stage 2: combine quarter-stats; softmax over j per column i.
// ---------------------------------------------------------------------------
__global__ __launch_bounds__(256)
void softmax_t(const float* __restrict__ sp, const float* __restrict__ st,
               bf16* __restrict__ pr) {
  const int m = blockIdx.x >> 2, iq = blockIdx.x & 3;
  const size_t PS = 4194304;
  const float sum = (st[m*8+0] + st[m*8+2]) + (st[m*8+4] + st[m*8+6]);
  const float sq  = (st[m*8+1] + st[m*8+3]) + (st[m*8+5] + st[m*8+7]);
  const float mean = sum * (1.f / 65536.f);
  const float var  = sq * (1.f / 65536.f) - mean * mean;
  const float inv  = rsqrtf(var + 1e-5f);

  const int tid = threadIdx.x;
  const int i  = iq * 64 + (tid & 63);
  const int jq = tid >> 6;
  const float* cb = sp + (size_t)m * 65536 + i;

  float e[64];
  float se = 0.f;
  #pragma unroll
  for (int jj = 0; jj < 64; ++jj) {
    const size_t o = (size_t)(jq * 64 + jj) * 256;
    const float v = (cb[o] + cb[PS + o]) + (cb[2 * PS + o] + cb[3 * PS + o]);
    e[jj] = __expf((v - mean) * inv);
    se += e[jj];
  }
  __shared__ float seb[256];
  seb[tid] = se;
  __syncthreads();
  const int c = tid & 63;
  const float rvs = 1.f / ((seb[c] + seb[c + 64]) + (seb[c + 128] + seb[c + 192]));
  bf16* pc = pr + (size_t)m * 65536 + i;
  #pragma unroll
  for (int jj = 0; jj < 64; ++jj)
    pc[(size_t)(jq * 64 + jj) * 256] = __float2bfloat16(e[jj] * rvs);
}

// ---------------------------------------------------------------------------
// Host orchestration
// ---------------------------------------------------------------------------
extern "C" void kernel_launch(void* const* d_in, const int* in_sizes, int n_in,
                              void* d_out, int out_size, void* d_ws, size_t ws_size,
                              hipStream_t stream)
{
  const float* S     = (const float*)d_in[0];
  const float* SKV   = (const float*)d_in[1];
  const float* T     = (const float*)d_in[2];
  const float* TKV   = (const float*)d_in[3];
  const float* Wq    = (const float*)d_in[4];
  const float* Wk    = (const float*)d_in[5];
  const float* Wv    = (const float*)d_in[6];
  const float* Wout  = (const float*)d_in[7];
  const float* Woutd = (const float*)d_in[8];
  float* out = (float*)d_out;

  const int Hd = 4, Dd = 256;
  const long long NC  = 4096ll * 1024;
  const long long BNC = 4 * NC;
  const long long HDN = 1048576;

  char* ws = (char*)d_ws;
  size_t off = 0;
  auto alloc = [&](size_t bytes) -> void* {
    void* pp = ws + off; off += (bytes + 255) & ~(size_t)255; return pp;
  };
  bf16*  Wqb    = (bf16*)alloc((size_t)Hd * Dd * Dd * 2);
  bf16*  Wkb    = (bf16*)alloc((size_t)Hd * Dd * Dd * 2);
  bf16*  Wvb    = (bf16*)alloc((size_t)Hd * Dd * Dd * 2);
  bf16*  Wpre   = (bf16*)alloc(2ull * 1024 * 1024 * 2);
  bf16*  QT     = (bf16*)alloc(2 * BNC * 2);          // [qi][b][h][i][n]
  bf16*  KT     = (bf16*)alloc(2 * BNC * 2);          // [ki][b][h][j][n]
  bf16*  Vc     = (bf16*)alloc(2 * BNC * 2);          // [vi][b][n][h*256+j]
  float* sparts = (float*)alloc(4ull * 4194304 * 4);  // 4 split-K partials of scT
  float* stats  = (float*)alloc(256ull * 2 * 4);
  bf16*  probsT = (bf16*)alloc(64ull * 65536 * 2);    // [pp][b][h][j][i]
  bf16*  Weff   = QT;  // reuse: QT dead after scores GEMM; [b][ki][qi][o][c]
  if (ws_size < off) return;

  // 1) weight conversions
  {
    const int w4 = (Hd * Dd * Dd) / 4;
    cvt3_f32_bf16<<<dim3((w4 + 255) / 256, 3), dim3(256), 0, stream>>>(
        Wq, Wk, Wv, (unsigned short*)Wqb, (long long)Hd * Dd * Dd, w4);
    wpre_kernel<<<dim3(4096, 2), dim3(256), 0, stream>>>(Wout, Woutd, Wpre);
  }

  GemmP g{};

  // 2) Q projection
  g.A = Wqb; g.B = S; g.A2 = nullptr; g.B2 = T; g.C = QT;
  g.K = 256; g.lda = 256; g.ldb = 1024; g.ldc = 4096; g.tilesN = 32; g.swz = 0;
  g.d0 = 4; g.d1 = 4; g.d2 = 2;
  g.sA0 = 65536; g.sA1 = 0;  g.sA2 = 0;   g.sA3 = 0;
  g.sB0 = 256;   g.sB1 = NC; g.sB2 = 0;   g.sB3 = 0;
  g.sC0 = HDN;   g.sC1 = NC; g.sC2 = BNC; g.sC3 = 0;
  g.zA = 0; g.zB = 0; g.zC = 0;
  g.scale = 1.f;
  gemm_bt<0, 0, 1><<<dim3(2 * 32, 32), dim3(256), 0, stream>>>(g);

  // 3) fused K+V projection
  {
    KVP kv{SKV, TKV, Wkb, Wvb, KT, Vc};
    kv_fused<<<dim3(64, 32), dim3(256), 0, stream>>>(kv);
  }

  // 4) scores split-K=4 on the phased 256-tile kernel (best measured).
  G256P h{};
  h.A = KT; h.B = QT; h.C = sparts;
  h.lda = 4096; h.ldb = 4096; h.ldc = 256; h.nt = 16; h.tilesN = 1; h.swz = 0;
  h.d0 = 4; h.d1 = 4; h.d2 = 2;                       // (h, b, ki, qi)
  h.sA0 = HDN;   h.sA1 = NC;     h.sA2 = BNC;     h.sA3 = 0;
  h.sB0 = HDN;   h.sB1 = NC;     h.sB2 = 0;       h.sB3 = BNC;
  h.sC0 = 65536; h.sC1 = 262144; h.sC2 = 1048576; h.sC3 = 2097152;
  h.zA = 1024; h.zB = 1024; h.zC = 4194304;
  h.scale = 0.03125f;
  gemm256_bt<1><<<dim3(1, 64, 4), dim3(512), 0, stream>>>(h);

  // 5) stats + softmax
  stats_quarter<<<dim3(256), dim3(256), 0, stream>>>(sparts, stats);
  softmax_t<<<dim3(256), dim3(256), 0, stream>>>(sparts, stats, probsT);

  // 6) Weff[b][ki][qi][o][h*256+j] = sum_i Wpre[qi][o][h*256+i] * probsT[2qi+ki][b][h][j][i]
  g.A = Wpre; g.B = probsT; g.A2 = nullptr; g.B2 = nullptr; g.C = Weff;
  g.K = 256; g.lda = 1024; g.ldb = 256; g.ldc = 1024; g.tilesN = 2; g.swz = 0;
  g.d0 = 4; g.d1 = 4; g.d2 = 2;                       // (h, b, ki, qi)
  g.sA0 = 256;   g.sA1 = 0;       g.sA2 = 0;       g.sA3 = 1048576;
  g.sB0 = 65536; g.sB1 = 262144;  g.sB2 = 1048576; g.sB3 = 2097152;
  g.sC0 = 256;   g.sC1 = 4194304; g.sC2 = 2097152; g.sC3 = 1048576;
  g.zA = 0; g.zB = 0; g.zC = 0;
  g.scale = 1.f;
  gemm_bt<0, 0, 0><<<dim3(8 * 2, 64), dim3(256), 0, stream>>>(g);

  // 7) final (128^2): out[qi+2ki][b][n][o] = sum_c Vc[ki][b][n][c] * Weff[b][ki][qi][o][c]
  g.A = Vc; g.B = Weff; g.C = out;
  g.K = 1024; g.lda = 1024; g.ldb = 1024; g.ldc = 1024; g.tilesN = 8; g.swz = 1;
  g.d0 = 2; g.d1 = 4; g.d2 = 2;                       // (qi, b, ki)
  g.sA0 = 0;       g.sA1 = NC;      g.sA2 = BNC;     g.sA3 = 0;
  g.sB0 = 1048576; g.sB1 = 4194304; g.sB2 = 2097152; g.sB3 = 0;
  g.sC0 = BNC;     g.sC1 = NC;      g.sC2 = 2 * BNC; g.sC3 = 0;
  g.zA = 0; g.zB = 0; g.zC = 0;
  g.scale = 1.f;
  gemm_bt<1, 0, 0><<<dim3(32 * 8, 16), dim3(256), 0, stream>>>(g);

  (void)in_sizes; (void)n_in; (void)out_size;
}

// Round 10
// 388.879 us; speedup vs baseline: 1.3434x; 1.3434x over previous
//
#include <hip/hip_runtime.h>
#include <hip/hip_bf16.h>
#include <cstdint>

using bf16 = __hip_bfloat16;
typedef __attribute__((ext_vector_type(8))) short bf16x8v;
typedef __attribute__((ext_vector_type(4))) float f32x4v;

__device__ __forceinline__ void gload_lds16(const void* g, void* l) {
  __builtin_amdgcn_global_load_lds(
      (const __attribute__((address_space(1))) void*)g,
      (__attribute__((address_space(3))) void*)l, 16, 0, 0);
}

__device__ __forceinline__ unsigned short f2bu(float x) {
  union { __hip_bfloat16 h; unsigned short u; } cv;
  cv.h = __float2bfloat16(x);
  return cv.u;
}

__device__ __forceinline__ float b2f(short u) {
  union { float f; unsigned int i; } cv;
  cv.i = ((unsigned int)(unsigned short)u) << 16;
  return cv.f;
}

__device__ __forceinline__ bf16x8v cvt8(const f32x4v lo, const f32x4v hi) {
  bf16x8v t;
  t[0] = (short)f2bu(lo[0]); t[1] = (short)f2bu(lo[1]);
  t[2] = (short)f2bu(lo[2]); t[3] = (short)f2bu(lo[3]);
  t[4] = (short)f2bu(hi[0]); t[5] = (short)f2bu(hi[1]);
  t[6] = (short)f2bu(hi[2]); t[7] = (short)f2bu(hi[3]);
  return t;
}

// ---------------------------------------------------------------------------
// Generic batched "bt" GEMM (128x128 tile, 4 waves, 16x16x32 MFMA core).
// C = scale * A * B^T. Proven best structure (R7: final GEMM ~170us, 0 LDS
// conflicts). Journal: (256,5) forced VGPR 60->48 -> MfmaUtil 21%, final
// 265us (R9 regression); 32x32x16 core -> 1.7e7 bank conflicts (R8).
// Keep (256,4) + 16x16x32 + XOR-slot swizzle.
// ---------------------------------------------------------------------------
struct GemmP {
  const void* A; const void* B; const void* A2; const void* B2; void* C;
  int K, lda, ldb, ldc, tilesN, swz;
  int d0, d1, d2;
  long long sA0, sA1, sA2, sA3;
  long long sB0, sB1, sB2, sB3;
  long long sC0, sC1, sC2, sC3;
  long long zA, zB, zC;
  float scale;
};

template<int OUT_F32, int AF32, int BF32>
__global__ __launch_bounds__(256, 4)
void gemm_bt(GemmP p)
{
  constexpr int EA = AF32 ? 4 : 2;
  constexpr int EB = BF32 ? 4 : 2;
  constexpr int ABYTES = 128 * 64 * EA;
  constexpr int BBYTES = 128 * 64 * EB;
  constexpr int SEGA = ABYTES / 4096;
  constexpr int SEGB = BBYTES / 4096;
  __shared__ __attribute__((aligned(1024))) char smem[ABYTES + BBYTES];
  const int tid  = threadIdx.x;
  const int lane = tid & 63;
  const int wid  = tid >> 6;

  int bx = blockIdx.x;
  if (p.swz) {
    const int nx = gridDim.x;
    const int q = nx >> 3, r = nx & 7;
    const int xcd = bx & 7, loc = bx >> 3;
    bx = (xcd < r ? xcd * (q + 1) : r * (q + 1) + (xcd - r) * q) + loc;
  }
  const int tn = bx % p.tilesN;
  const int tm = bx / p.tilesN;
  int idx = blockIdx.y;
  const int i0 = idx % p.d0; idx /= p.d0;
  const int i1 = idx % p.d1; idx /= p.d1;
  const int i2 = idx % p.d2;
  const int i3 = idx / p.d2;

  const char* Abase = (const char*)((p.A2 && i2) ? p.A2 : p.A);
  const char* Bbase = (const char*)((p.B2 && i2) ? p.B2 : p.B);
  const long long offA = (long long)i0*p.sA0 + (long long)i1*p.sA1 +
                         (long long)i2*p.sA2 + (long long)i3*p.sA3 +
                         (long long)blockIdx.z*p.zA;
  const long long offB = (long long)i0*p.sB0 + (long long)i1*p.sB1 +
                         (long long)i2*p.sB2 + (long long)i3*p.sB3 +
                         (long long)blockIdx.z*p.zB;
  const char* Am = Abase + offA * EA;
  const char* Bm = Bbase + offB * EB;
  const int bm = tm * 128, bn = tn * 128;

  const char* asrc[SEGA]; int aseg[SEGA];
  #pragma unroll
  for (int r = 0; r < SEGA; ++r) {
    const int oseg = (wid * SEGA + r) * 1024;
    const int o = oseg + lane * 16;
    int row, srcoff;
    if constexpr (AF32) { row = o >> 8; const int s = (o >> 4) & 15; srcoff = (s ^ (row & 15)) * 4; }
    else               { row = o >> 7; const int s = (o >> 4) & 7;  srcoff = (s ^ (row & 7)) * 8;  }
    aseg[r] = oseg;
    asrc[r] = Am + ((long long)(bm + row) * p.lda + srcoff) * EA;
  }
  const char* bsrc[SEGB]; int bseg[SEGB];
  #pragma unroll
  for (int r = 0; r < SEGB; ++r) {
    const int oseg = (wid * SEGB + r) * 1024;
    const int o = oseg + lane * 16;
    int row, srcoff;
    if constexpr (BF32) { row = o >> 8; const int s = (o >> 4) & 15; srcoff = (s ^ (row & 15)) * 4; }
    else               { row = o >> 7; const int s = (o >> 4) & 7;  srcoff = (s ^ (row & 7)) * 8;  }
    bseg[r] = oseg;
    bsrc[r] = Bm + ((long long)(bn + row) * p.ldb + srcoff) * EB;
  }

  f32x4v acc[4][4];
  #pragma unroll
  for (int i = 0; i < 4; ++i)
    #pragma unroll
    for (int j = 0; j < 4; ++j) acc[i][j] = (f32x4v){0.f, 0.f, 0.f, 0.f};

  const int wr = wid >> 1, wc = wid & 1;
  const int fr_a = wr * 64 + (lane & 15);
  const int fr_b = wc * 64 + (lane & 15);
  const int fch  = lane >> 4;

  const int nK = p.K / 64;
  for (int kt = 0; kt < nK; ++kt) {
    #pragma unroll
    for (int r = 0; r < SEGA; ++r) { gload_lds16(asrc[r], smem + aseg[r]); asrc[r] += 64 * EA; }
    #pragma unroll
    for (int r = 0; r < SEGB; ++r) { gload_lds16(bsrc[r], smem + ABYTES + bseg[r]); bsrc[r] += 64 * EB; }
    __syncthreads();
    #pragma unroll
    for (int kk = 0; kk < 2; ++kk) {
      bf16x8v a[4], b[4];
      #pragma unroll
      for (int mi = 0; mi < 4; ++mi) {
        const int row = fr_a + mi * 16;
        if constexpr (AF32) {
          const int c2 = (fch + kk * 4) * 2;
          const f32x4v lo = *(const f32x4v*)(smem + row * 256 + ((c2 ^ (row & 15)) << 4));
          const f32x4v hi = *(const f32x4v*)(smem + row * 256 + (((c2 + 1) ^ (row & 15)) << 4));
          a[mi] = cvt8(lo, hi);
        } else {
          a[mi] = *(const bf16x8v*)(smem + row * 128 + (((fch + kk * 4) ^ (row & 7)) << 4));
        }
      }
      #pragma unroll
      for (int ni = 0; ni < 4; ++ni) {
        const int row = fr_b + ni * 16;
        if constexpr (BF32) {
          const int c2 = (fch + kk * 4) * 2;
          const f32x4v lo = *(const f32x4v*)(smem + ABYTES + row * 256 + ((c2 ^ (row & 15)) << 4));
          const f32x4v hi = *(const f32x4v*)(smem + ABYTES + row * 256 + (((c2 + 1) ^ (row & 15)) << 4));
          b[ni] = cvt8(lo, hi);
        } else {
          b[ni] = *(const bf16x8v*)(smem + ABYTES + row * 128 + (((fch + kk * 4) ^ (row & 7)) << 4));
        }
      }
      #pragma unroll
      for (int mi = 0; mi < 4; ++mi)
        #pragma unroll
        for (int ni = 0; ni < 4; ++ni)
          acc[mi][ni] = __builtin_amdgcn_mfma_f32_16x16x32_bf16(a[mi], b[ni], acc[mi][ni], 0, 0, 0);
    }
    __syncthreads();
  }

  const long long coff = (long long)i0*p.sC0 + (long long)i1*p.sC1 +
                         (long long)i2*p.sC2 + (long long)i3*p.sC3 +
                         (long long)blockIdx.z*p.zC;
  const int col0 = bn + wc * 64 + (lane & 15);
  const int row0 = bm + wr * 64 + ((lane >> 4) << 2);
  if (OUT_F32) {
    float* Cp = (float*)p.C + coff;
    #pragma unroll
    for (int mi = 0; mi < 4; ++mi)
      #pragma unroll
      for (int ni = 0; ni < 4; ++ni)
        #pragma unroll
        for (int j = 0; j < 4; ++j)
          Cp[(size_t)(row0 + mi*16 + j) * p.ldc + (col0 + ni*16)] = acc[mi][ni][j] * p.scale;
  } else {
    bf16* Cp = (bf16*)p.C + coff;
    #pragma unroll
    for (int mi = 0; mi < 4; ++mi)
      #pragma unroll
      for (int ni = 0; ni < 4; ++ni)
        #pragma unroll
        for (int j = 0; j < 4; ++j)
          Cp[(size_t)(row0 + mi*16 + j) * p.ldc + (col0 + ni*16)] =
              __float2bfloat16(acc[mi][ni][j] * p.scale);
  }
}

// ---------------------------------------------------------------------------
// 256x256-tile, 8-wave, PHASED double-buffered GEMM (scores GEMM only).
// ---------------------------------------------------------------------------
struct G256P {
  const bf16* A; const bf16* B; void* C;
  int lda, ldb, ldc, nt, tilesN, swz;
  int d0, d1, d2;
  long long sA0, sA1, sA2, sA3;
  long long sB0, sB1, sB2, sB3;
  long long sC0, sC1, sC2, sC3;
  long long zA, zB, zC;
  float scale;
};

template<int OUT_F32>
__global__ __launch_bounds__(512, 1)
void gemm256_bt(G256P p)
{
  __shared__ __attribute__((aligned(1024))) char smem[131072];
  const int tid = threadIdx.x, lane = tid & 63, wid = tid >> 6;

  int bx = blockIdx.x;
  if (p.swz) {
    const int nx = gridDim.x;
    const int q = nx >> 3, r = nx & 7;
    const int xcd = bx & 7, loc = bx >> 3;
    bx = (xcd < r ? xcd * (q + 1) : r * (q + 1) + (xcd - r) * q) + loc;
  }
  const int tn = bx % p.tilesN, tm = bx / p.tilesN;
  int idx = blockIdx.y;
  const int i0 = idx % p.d0; idx /= p.d0;
  const int i1 = idx % p.d1; idx /= p.d1;
  const int i2 = idx % p.d2;
  const int i3 = idx / p.d2;

  const bf16* Am = p.A + ((long long)i0*p.sA0 + (long long)i1*p.sA1 +
                          (long long)i2*p.sA2 + (long long)i3*p.sA3 +
                          (long long)blockIdx.z*p.zA) + (long long)tm * 256 * p.lda;
  const bf16* Bm = p.B + ((long long)i0*p.sB0 + (long long)i1*p.sB1 +
                          (long long)i2*p.sB2 + (long long)i3*p.sB3 +
                          (long long)blockIdx.z*p.zB) + (long long)tn * 256 * p.ldb;

  int arow[2][2]; int ach[2][2];
  #pragma unroll
  for (int hh = 0; hh < 2; ++hh)
    #pragma unroll
    for (int l = 0; l < 2; ++l) {
      const int seg = hh * 16 + wid * 2 + l;
      const int o = seg * 1024 + lane * 16;
      const int row = o >> 7;
      arow[hh][l] = row;
      ach[hh][l] = ((o >> 4) & 7) ^ (row & 7);
    }

  auto stageA = [&](int kt, int hh, int buf) {
    #pragma unroll
    for (int l = 0; l < 2; ++l) {
      const int seg = hh * 16 + wid * 2 + l;
      gload_lds16(Am + (long long)arow[hh][l] * p.lda + ach[hh][l] * 8 + kt * 64,
                  smem + buf * 32768 + seg * 1024);
    }
  };
  auto stageB = [&](int kt, int hh, int buf) {
    #pragma unroll
    for (int l = 0; l < 2; ++l) {
      const int seg = hh * 16 + wid * 2 + l;
      gload_lds16(Bm + (long long)arow[hh][l] * p.ldb + ach[hh][l] * 8 + kt * 64,
                  smem + 65536 + buf * 32768 + seg * 1024);
    }
  };

  stageA(0, 0, 0); stageA(0, 1, 0);
  stageB(0, 0, 0); stageB(0, 1, 0);
  if (p.nt > 1) { stageB(1, 0, 1); stageB(1, 1, 1); }
  asm volatile("s_waitcnt vmcnt(0)" ::: "memory");
  __builtin_amdgcn_s_barrier();

  f32x4v acc[8][4];
  #pragma unroll
  for (int i = 0; i < 8; ++i)
    #pragma unroll
    for (int j = 0; j < 4; ++j) acc[i][j] = (f32x4v){0.f, 0.f, 0.f, 0.f};

  const int wr = wid >> 2, wc = wid & 3;
  const int rA = wr * 128 + (lane & 15);
  const int rB = wc * 64 + (lane & 15);
  const int fch = lane >> 4;

  bf16x8v bfr[2][4];

  for (int t = 0; t < p.nt; ++t) {
    const int pb = t & 1;
    const char* Ab = smem + pb * 32768;
    const char* Bb = smem + 65536 + pb * 32768;

    #pragma unroll
    for (int q = 0; q < 4; ++q) {
      if (q == 0) {
        #pragma unroll
        for (int kk = 0; kk < 2; ++kk)
          #pragma unroll
          for (int ni = 0; ni < 4; ++ni) {
            const int row = rB + ni * 16;
            bfr[kk][ni] = *(const bf16x8v*)(Bb + row * 128 +
                                            (((fch + kk * 4) ^ (row & 7)) << 4));
          }
      }
      bf16x8v afr[2][2];
      #pragma unroll
      for (int kk = 0; kk < 2; ++kk)
        #pragma unroll
        for (int s = 0; s < 2; ++s) {
          const int row = rA + (q * 2 + s) * 16;
          afr[kk][s] = *(const bf16x8v*)(Ab + row * 128 +
                                         (((fch + kk * 4) ^ (row & 7)) << 4));
        }
      if (q == 0 && t + 1 < p.nt) stageA(t + 1, 0, pb ^ 1);
      if (q == 1 && t + 1 < p.nt) stageA(t + 1, 1, pb ^ 1);
      if (q == 2 && t + 2 < p.nt) stageB(t + 2, 0, pb);
      if (q == 3) {
        if (t + 2 < p.nt) {
          stageB(t + 2, 1, pb);
          asm volatile("s_waitcnt vmcnt(4)" ::: "memory");
        } else {
          asm volatile("s_waitcnt vmcnt(0)" ::: "memory");
        }
      }
      __builtin_amdgcn_s_barrier();
      asm volatile("s_waitcnt lgkmcnt(0)" ::: "memory");
      __builtin_amdgcn_sched_barrier(0);
      __builtin_amdgcn_s_setprio(1);
      #pragma unroll
      for (int kk = 0; kk < 2; ++kk)
        #pragma unroll
        for (int s = 0; s < 2; ++s)
          #pragma unroll
          for (int ni = 0; ni < 4; ++ni)
            acc[q * 2 + s][ni] = __builtin_amdgcn_mfma_f32_16x16x32_bf16(
                afr[kk][s], bfr[kk][ni], acc[q * 2 + s][ni], 0, 0, 0);
      __builtin_amdgcn_s_setprio(0);
      __builtin_amdgcn_sched_barrier(0);
      __builtin_amdgcn_s_barrier();
    }
  }

  const long long coff = (long long)i0*p.sC0 + (long long)i1*p.sC1 +
                         (long long)i2*p.sC2 + (long long)i3*p.sC3 +
                         (long long)blockIdx.z*p.zC;
  const int col0 = tn * 256 + wc * 64 + (lane & 15);
  const int row0 = tm * 256 + wr * 128 + ((lane >> 4) << 2);
  if (OUT_F32) {
    float* Cp = (float*)p.C + coff;
    #pragma unroll
    for (int mi = 0; mi < 8; ++mi)
      #pragma unroll
      for (int ni = 0; ni < 4; ++ni)
        #pragma unroll
        for (int j = 0; j < 4; ++j)
          Cp[(size_t)(row0 + mi*16 + j) * p.ldc + (col0 + ni*16)] = acc[mi][ni][j] * p.scale;
  } else {
    bf16* Cp = (bf16*)p.C + coff;
    #pragma unroll
    for (int mi = 0; mi < 8; ++mi)
      #pragma unroll
      for (int ni = 0; ni < 4; ++ni)
        #pragma unroll
        for (int j = 0; j < 4; ++j)
          Cp[(size_t)(row0 + mi*16 + j) * p.ldc + (col0 + ni*16)] =
              __float2bfloat16(acc[mi][ni][j] * p.scale);
  }
}

// ---------------------------------------------------------------------------
// Fused K+V projection (shared X tile).
// ---------------------------------------------------------------------------
struct KVP {
  const float* X0; const float* X1;
  const bf16* Wk; const bf16* Wv;
  bf16* KT; bf16* Vc;
};

__global__ __launch_bounds__(256, 2)
void kv_fused(KVP p)
{
  __shared__ __attribute__((aligned(1024))) char smem[65536];
  const int tid = threadIdx.x, lane = tid & 63, wid = tid >> 6;
  const int jt = blockIdx.x & 1, nt = blockIdx.x >> 1;
  int idx = blockIdx.y;
  const int h = idx & 3; idx >>= 2;
  const int b = idx & 3; idx >>= 2;
  const int vi = idx;
  const float* X = (vi ? p.X1 : p.X0) + (size_t)b * 4194304 + (size_t)h * 256;
  const bf16* Wk = p.Wk + (size_t)h * 65536;
  const bf16* Wv = p.Wv + (size_t)h * 65536;
  const int n0 = nt * 128, j0 = jt * 128;

  const float* xsrc[8];
  #pragma unroll
  for (int r = 0; r < 8; ++r) {
    const int o = (wid * 8 + r) * 1024 + lane * 16;
    const int row = o >> 8, s = (o >> 4) & 15;
    xsrc[r] = X + (size_t)(n0 + row) * 1024 + (s ^ (row & 15)) * 4;
  }
  const bf16 *wksrc[4], *wvsrc[4];
  #pragma unroll
  for (int r = 0; r < 4; ++r) {
    const int o = (wid * 4 + r) * 1024 + lane * 16;
    const int row = o >> 7, s = (o >> 4) & 7;
    wksrc[r] = Wk + (size_t)(j0 + row) * 256 + (s ^ (row & 7)) * 8;
    wvsrc[r] = Wv + (size_t)(j0 + row) * 256 + (s ^ (row & 7)) * 8;
  }

  f32x4v accK[4][4], accV[4][4];
  #pragma unroll
  for (int i = 0; i < 4; ++i)
    #pragma unroll
    for (int j = 0; j < 4; ++j) {
      accK[i][j] = (f32x4v){0.f, 0.f, 0.f, 0.f};
      accV[i][j] = (f32x4v){0.f, 0.f, 0.f, 0.f};
    }

  const int wr = wid >> 1, wc = wid & 1;
  const int frW = wr * 64 + (lane & 15);
  const int frX = wc * 64 + (lane & 15);
  const int fch = lane >> 4;

  for (int kt = 0; kt < 4; ++kt) {
    #pragma unroll
    for (int r = 0; r < 8; ++r) { gload_lds16(xsrc[r], smem + (wid * 8 + r) * 1024); xsrc[r] += 64; }
    #pragma unroll
    for (int r = 0; r < 4; ++r) {
      gload_lds16(wksrc[r], smem + 32768 + (wid * 4 + r) * 1024); wksrc[r] += 64;
      gload_lds16(wvsrc[r], smem + 49152 + (wid * 4 + r) * 1024); wvsrc[r] += 64;
    }
    __syncthreads();
    #pragma unroll
    for (int kk = 0; kk < 2; ++kk) {
      bf16x8v wk[4], wv[4], x[4];
      #pragma unroll
      for (int mi = 0; mi < 4; ++mi) {
        const int row = frW + mi * 16;
        const int byo = row * 128 + (((fch + kk * 4) ^ (row & 7)) << 4);
        wk[mi] = *(const bf16x8v*)(smem + 32768 + byo);
        wv[mi] = *(const bf16x8v*)(smem + 49152 + byo);
      }
      #pragma unroll
      for (int ni = 0; ni < 4; ++ni) {
        const int row = frX + ni * 16;
        const int c2 = (fch + kk * 4) * 2;
        const f32x4v lo = *(const f32x4v*)(smem + row * 256 + ((c2 ^ (row & 15)) << 4));
        const f32x4v hi = *(const f32x4v*)(smem + row * 256 + (((c2 + 1) ^ (row & 15)) << 4));
        x[ni] = cvt8(lo, hi);
      }
      #pragma unroll
      for (int mi = 0; mi < 4; ++mi)
        #pragma unroll
        for (int ni = 0; ni < 4; ++ni) {
          accK[mi][ni] = __builtin_amdgcn_mfma_f32_16x16x32_bf16(wk[mi], x[ni], accK[mi][ni], 0, 0, 0);
          accV[ni][mi] = __builtin_amdgcn_mfma_f32_16x16x32_bf16(x[ni], wv[mi], accV[ni][mi], 0, 0, 0);
        }
    }
    __syncthreads();
  }

  const size_t kbase = (size_t)vi * 16777216 + (size_t)b * 4194304 + (size_t)h * 1048576;
  const size_t vbase = (size_t)vi * 16777216 + (size_t)b * 4194304;
  bf16* Kp = p.KT + kbase;
  bf16* Vp = p.Vc + vbase;
  const int rW = ((lane >> 4) << 2);
  #pragma unroll
  for (int mi = 0; mi < 4; ++mi)
    #pragma unroll
    for (int ni = 0; ni < 4; ++ni)
      #pragma unroll
      for (int j = 0; j < 4; ++j) {
        const int jrow = j0 + wr * 64 + mi * 16 + rW + j;
        const int ncol = n0 + wc * 64 + ni * 16 + (lane & 15);
        Kp[(size_t)jrow * 4096 + ncol] = __float2bfloat16(accK[mi][ni][j]);
        const int nrow = n0 + wc * 64 + ni * 16 + rW + j;
        const int jcol = j0 + wr * 64 + mi * 16 + (lane & 15);
        Vp[(size_t)nrow * 1024 + h * 256 + jcol] = __float2bfloat16(accV[ni][mi][j]);
      }
}

// ---------------------------------------------------------------------------
// weight conversions
// ---------------------------------------------------------------------------
__global__ void cvt3_f32_bf16(const float* __restrict__ a0, const float* __restrict__ a1,
                              const float* __restrict__ a2,
                              unsigned short* __restrict__ out, long long ostride, int n4) {
  const int i = blockIdx.x * 256 + threadIdx.x;
  if (i >= n4) return;
  const float* src = (blockIdx.y == 0) ? a0 : (blockIdx.y == 1) ? a1 : a2;
  const float4 v = ((const float4*)src)[i];
  ushort4 o;
  o.x = f2bu(v.x); o.y = f2bu(v.y); o.z = f2bu(v.z); o.w = f2bu(v.w);
  ((ushort4*)(out + (size_t)blockIdx.y * ostride))[i] = o;
}

__global__ void wpre_kernel(const float* __restrict__ Wout, const float* __restrict__ Woutd,
                            bf16* __restrict__ Wpre) {
  const int w = blockIdx.y;
  const int flat = blockIdx.x * 256 + threadIdx.x;
  const float* Wsrc = w ? Woutd : Wout;
  const int o  = flat >> 10;
  const int c2 = flat & 1023;
  const int h  = c2 >> 8;
  const int i  = c2 & 255;
  Wpre[(size_t)w * 1048576 + flat] = __float2bfloat16(Wsrc[o * 1024 + i * 4 + h]);
}

// ---------------------------------------------------------------------------
// Stage 1: per quarter-matrix sum/sumsq of z-summed scores (bf16 partials,
// fp32 accumulation; deterministic).
// ---------------------------------------------------------------------------
__global__ __launch_bounds__(256)
void stats_quarter(const bf16* __restrict__ sp, float* __restrict__ st) {
  const int m = blockIdx.x >> 2, q = blockIdx.x & 3;
  const size_t PS = 4194304;
  const bf16* s = sp + (size_t)m * 65536 + (size_t)q * 16384;
  const int tid = threadIdx.x, lane = tid & 63, w = tid >> 6;

  float sum = 0.f, sq = 0.f;
  for (int i = tid; i < 2048; i += 256) {
    const bf16x8v a = ((const bf16x8v*)s)[i];
    const bf16x8v b = ((const bf16x8v*)(s + PS))[i];
    const bf16x8v c = ((const bf16x8v*)(s + 2 * PS))[i];
    const bf16x8v d = ((const bf16x8v*)(s + 3 * PS))[i];
    #pragma unroll
    for (int e = 0; e < 8; ++e) {
      const float x = (b2f(a[e]) + b2f(b[e])) + (b2f(c[e]) + b2f(d[e]));
      sum += x;
      sq  += x * x;
    }
  }
  #pragma unroll
  for (int o = 32; o; o >>= 1) { sum += __shfl_xor(sum, o); sq += __shfl_xor(sq, o); }
  __shared__ float red[8];
  if (lane == 0) { red[w] = sum; red[4 + w] = sq; }
  __syncthreads();
  if (tid == 0) {
    st[blockIdx.x * 2]     = (red[0] + red[1]) + (red[2] + red[3]);
    st[blockIdx.x * 2 + 1] = (red[4] + red[5]) + (red[6] + red[7]);
  }
}

// ---------------------------------------------------------------------------
// Stage 2: combine quarter-stats; softmax over j per column i (bf16 partials).
// ---------------------------------------------------------------------------
__global__ __launch_bounds__(256)
void softmax_t(const bf16* __restrict__ sp, const float* __restrict__ st,
               bf16* __restrict__ pr) {
  const int m = blockIdx.x >> 2, iq = blockIdx.x & 3;
  const size_t PS = 4194304;
  const float sum = (st[m*8+0] + st[m*8+2]) + (st[m*8+4] + st[m*8+6]);
  const float sq  = (st[m*8+1] + st[m*8+3]) + (st[m*8+5] + st[m*8+7]);
  const float mean = sum * (1.f / 65536.f);
  const float var  = sq * (1.f / 65536.f) - mean * mean;
  const float inv  = rsqrtf(var + 1e-5f);

  const int tid = threadIdx.x;
  const int i  = iq * 64 + (tid & 63);
  const int jq = tid >> 6;
  const bf16* cb = sp + (size_t)m * 65536 + i;

  float e[64];
  float se = 0.f;
  #pragma unroll
  for (int jj = 0; jj < 64; ++jj) {
    const size_t o = (size_t)(jq * 64 + jj) * 256;
    const float v = (__bfloat162float(cb[o]) + __bfloat162float(cb[PS + o])) +
                    (__bfloat162float(cb[2 * PS + o]) + __bfloat162float(cb[3 * PS + o]));
    e[jj] = __expf((v - mean) * inv);
    se += e[jj];
  }
  __shared__ float seb[256];
  seb[tid] = se;
  __syncthreads();
  const int c = tid & 63;
  const float rvs = 1.f / ((seb[c] + seb[c + 64]) + (seb[c + 128] + seb[c + 192]));
  bf16* pc = pr + (size_t)m * 65536 + i;
  #pragma unroll
  for (int jj = 0; jj < 64; ++jj)
    pc[(size_t)(jq * 64 + jj) * 256] = __float2bfloat16(e[jj] * rvs);
}

// ---------------------------------------------------------------------------
// Host orchestration
// ---------------------------------------------------------------------------
extern "C" void kernel_launch(void* const* d_in, const int* in_sizes, int n_in,
                              void* d_out, int out_size, void* d_ws, size_t ws_size,
                              hipStream_t stream)
{
  const float* S     = (const float*)d_in[0];
  const float* SKV   = (const float*)d_in[1];
  const float* T     = (const float*)d_in[2];
  const float* TKV   = (const float*)d_in[3];
  const float* Wq    = (const float*)d_in[4];
  const float* Wk    = (const float*)d_in[5];
  const float* Wv    = (const float*)d_in[6];
  const float* Wout  = (const float*)d_in[7];
  const float* Woutd = (const float*)d_in[8];
  float* out = (float*)d_out;

  const int Hd = 4, Dd = 256;
  const long long NC  = 4096ll * 1024;
  const long long BNC = 4 * NC;
  const long long HDN = 1048576;

  char* ws = (char*)d_ws;
  size_t off = 0;
  auto alloc = [&](size_t bytes) -> void* {
    void* pp = ws + off; off += (bytes + 255) & ~(size_t)255; return pp;
  };
  bf16*  Wqb    = (bf16*)alloc((size_t)Hd * Dd * Dd * 2);
  bf16*  Wkb    = (bf16*)alloc((size_t)Hd * Dd * Dd * 2);
  bf16*  Wvb    = (bf16*)alloc((size_t)Hd * Dd * Dd * 2);
  bf16*  Wpre   = (bf16*)alloc(2ull * 1024 * 1024 * 2);
  bf16*  QT     = (bf16*)alloc(2 * BNC * 2);          // [qi][b][h][i][n]
  bf16*  KT     = (bf16*)alloc(2 * BNC * 2);          // [ki][b][h][j][n]
  bf16*  Vc     = (bf16*)alloc(2 * BNC * 2);          // [vi][b][n][h*256+j]
  bf16*  sparts = (bf16*)alloc(4ull * 4194304 * 2);   // 4 split-K partials (bf16)
  float* stats  = (float*)alloc(256ull * 2 * 4);
  bf16*  probsT = (bf16*)alloc(64ull * 65536 * 2);    // [pp][b][h][j][i]
  bf16*  Weff   = QT;  // reuse: QT dead after scores GEMM; [b][ki][qi][o][c]
  if (ws_size < off) return;

  // 1) weight conversions
  {
    const int w4 = (Hd * Dd * Dd) / 4;
    cvt3_f32_bf16<<<dim3((w4 + 255) / 256, 3), dim3(256), 0, stream>>>(
        Wq, Wk, Wv, (unsigned short*)Wqb, (long long)Hd * Dd * Dd, w4);
    wpre_kernel<<<dim3(4096, 2), dim3(256), 0, stream>>>(Wout, Woutd, Wpre);
  }

  GemmP g{};

  // 2) Q projection
  g.A = Wqb; g.B = S; g.A2 = nullptr; g.B2 = T; g.C = QT;
  g.K = 256; g.lda = 256; g.ldb = 1024; g.ldc = 4096; g.tilesN = 32; g.swz = 0;
  g.d0 = 4; g.d1 = 4; g.d2 = 2;
  g.sA0 = 65536; g.sA1 = 0;  g.sA2 = 0;   g.sA3 = 0;
  g.sB0 = 256;   g.sB1 = NC; g.sB2 = 0;   g.sB3 = 0;
  g.sC0 = HDN;   g.sC1 = NC; g.sC2 = BNC; g.sC3 = 0;
  g.zA = 0; g.zB = 0; g.zC = 0;
  g.scale = 1.f;
  gemm_bt<0, 0, 1><<<dim3(2 * 32, 32), dim3(256), 0, stream>>>(g);

  // 3) fused K+V projection
  {
    KVP kv{SKV, TKV, Wkb, Wvb, KT, Vc};
    kv_fused<<<dim3(64, 32), dim3(256), 0, stream>>>(kv);
  }

  // 4) scores split-K=4 on the phased 256-tile kernel; bf16 partials.
  G256P h{};
  h.A = KT; h.B = QT; h.C = sparts;
  h.lda = 4096; h.ldb = 4096; h.ldc = 256; h.nt = 16; h.tilesN = 1; h.swz = 0;
  h.d0 = 4; h.d1 = 4; h.d2 = 2;                       // (h, b, ki, qi)
  h.sA0 = HDN;   h.sA1 = NC;     h.sA2 = BNC;     h.sA3 = 0;
  h.sB0 = HDN;   h.sB1 = NC;     h.sB2 = 0;       h.sB3 = BNC;
  h.sC0 = 65536; h.sC1 = 262144; h.sC2 = 1048576; h.sC3 = 2097152;
  h.zA = 1024; h.zB = 1024; h.zC = 4194304;
  h.scale = 0.03125f;
  gemm256_bt<0><<<dim3(1, 64, 4), dim3(512), 0, stream>>>(h);

  // 5) stats + softmax (read bf16 partials)
  stats_quarter<<<dim3(256), dim3(256), 0, stream>>>(sparts, stats);
  softmax_t<<<dim3(256), dim3(256), 0, stream>>>(sparts, stats, probsT);

  // 6) Weff[b][ki][qi][o][h*256+j] = sum_i Wpre[qi][o][h*256+i] * probsT[2qi+ki][b][h][j][i]
  g.A = Wpre; g.B = probsT; g.A2 = nullptr; g.B2 = nullptr; g.C = Weff;
  g.K = 256; g.lda = 1024; g.ldb = 256; g.ldc = 1024; g.tilesN = 2; g.swz = 0;
  g.d0 = 4; g.d1 = 4; g.d2 = 2;                       // (h, b, ki, qi)
  g.sA0 = 256;   g.sA1 = 0;       g.sA2 = 0;       g.sA3 = 1048576;
  g.sB0 = 65536; g.sB1 = 262144;  g.sB2 = 1048576; g.sB3 = 2097152;
  g.sC0 = 256;   g.sC1 = 4194304; g.sC2 = 2097152; g.sC3 = 1048576;
  g.zA = 0; g.zB = 0; g.zC = 0;
  g.scale = 1.f;
  gemm_bt<0, 0, 0><<<dim3(8 * 2, 64), dim3(256), 0, stream>>>(g);

  // 7) final (128^2): out[qi+2ki][b][n][o] = sum_c Vc[ki][b][n][c] * Weff[b][ki][qi][o][c]
  g.A = Vc; g.B = Weff; g.C = out;
  g.K = 1024; g.lda = 1024; g.ldb = 1024; g.ldc = 1024; g.tilesN = 8; g.swz = 1;
  g.d0 = 2; g.d1 = 4; g.d2 = 2;                       // (qi, b, ki)
  g.sA0 = 0;       g.sA1 = NC;      g.sA2 = BNC;     g.sA3 = 0;
  g.sB0 = 1048576; g.sB1 = 4194304; g.sB2 = 2097152; g.sB3 = 0;
  g.sC0 = BNC;     g.sC1 = NC;      g.sC2 = 2 * BNC; g.sC3 = 0;
  g.zA = 0; g.zB = 0; g.zC = 0;
  g.scale = 1.f;
  gemm_bt<1, 0, 0><<<dim3(32 * 8, 16), dim3(256), 0, stream>>>(g);

  (void)in_sizes; (void)n_in; (void)out_size;
}

// Round 11
// 384.007 us; speedup vs baseline: 1.3604x; 1.0127x over previous
//
#include <hip/hip_runtime.h>
#include <hip/hip_bf16.h>
#include <cstdint>

using bf16 = __hip_bfloat16;
typedef __attribute__((ext_vector_type(8))) short bf16x8v;
typedef __attribute__((ext_vector_type(4))) float f32x4v;

__device__ __forceinline__ void gload_lds16(const void* g, void* l) {
  __builtin_amdgcn_global_load_lds(
      (const __attribute__((address_space(1))) void*)g,
      (__attribute__((address_space(3))) void*)l, 16, 0, 0);
}

__device__ __forceinline__ unsigned short f2bu(float x) {
  union { __hip_bfloat16 h; unsigned short u; } cv;
  cv.h = __float2bfloat16(x);
  return cv.u;
}

__device__ __forceinline__ float b2f(short u) {
  union { float f; unsigned int i; } cv;
  cv.i = ((unsigned int)(unsigned short)u) << 16;
  return cv.f;
}

__device__ __forceinline__ bf16x8v cvt8(const f32x4v lo, const f32x4v hi) {
  bf16x8v t;
  t[0] = (short)f2bu(lo[0]); t[1] = (short)f2bu(lo[1]);
  t[2] = (short)f2bu(lo[2]); t[3] = (short)f2bu(lo[3]);
  t[4] = (short)f2bu(hi[0]); t[5] = (short)f2bu(hi[1]);
  t[6] = (short)f2bu(hi[2]); t[7] = (short)f2bu(hi[3]);
  return t;
}

// ---------------------------------------------------------------------------
// Generic batched "bt" GEMM (128x128 tile, 4 waves, 16x16x32 MFMA core).
// Journal: (256,5)->VGPR48->regression (R9); 32x32 core->bank conflicts (R8).
// ---------------------------------------------------------------------------
struct GemmP {
  const void* A; const void* B; const void* A2; const void* B2; void* C;
  int K, lda, ldb, ldc, tilesN, swz;
  int d0, d1, d2;
  long long sA0, sA1, sA2, sA3;
  long long sB0, sB1, sB2, sB3;
  long long sC0, sC1, sC2, sC3;
  long long zA, zB, zC;
  float scale;
};

template<int OUT_F32, int AF32, int BF32>
__global__ __launch_bounds__(256, 4)
void gemm_bt(GemmP p)
{
  constexpr int EA = AF32 ? 4 : 2;
  constexpr int EB = BF32 ? 4 : 2;
  constexpr int ABYTES = 128 * 64 * EA;
  constexpr int BBYTES = 128 * 64 * EB;
  constexpr int SEGA = ABYTES / 4096;
  constexpr int SEGB = BBYTES / 4096;
  __shared__ __attribute__((aligned(1024))) char smem[ABYTES + BBYTES];
  const int tid  = threadIdx.x;
  const int lane = tid & 63;
  const int wid  = tid >> 6;

  int bx = blockIdx.x;
  if (p.swz) {
    const int nx = gridDim.x;
    const int q = nx >> 3, r = nx & 7;
    const int xcd = bx & 7, loc = bx >> 3;
    bx = (xcd < r ? xcd * (q + 1) : r * (q + 1) + (xcd - r) * q) + loc;
  }
  const int tn = bx % p.tilesN;
  const int tm = bx / p.tilesN;
  int idx = blockIdx.y;
  const int i0 = idx % p.d0; idx /= p.d0;
  const int i1 = idx % p.d1; idx /= p.d1;
  const int i2 = idx % p.d2;
  const int i3 = idx / p.d2;

  const char* Abase = (const char*)((p.A2 && i2) ? p.A2 : p.A);
  const char* Bbase = (const char*)((p.B2 && i2) ? p.B2 : p.B);
  const long long offA = (long long)i0*p.sA0 + (long long)i1*p.sA1 +
                         (long long)i2*p.sA2 + (long long)i3*p.sA3 +
                         (long long)blockIdx.z*p.zA;
  const long long offB = (long long)i0*p.sB0 + (long long)i1*p.sB1 +
                         (long long)i2*p.sB2 + (long long)i3*p.sB3 +
                         (long long)blockIdx.z*p.zB;
  const char* Am = Abase + offA * EA;
  const char* Bm = Bbase + offB * EB;
  const int bm = tm * 128, bn = tn * 128;

  const char* asrc[SEGA]; int aseg[SEGA];
  #pragma unroll
  for (int r = 0; r < SEGA; ++r) {
    const int oseg = (wid * SEGA + r) * 1024;
    const int o = oseg + lane * 16;
    int row, srcoff;
    if constexpr (AF32) { row = o >> 8; const int s = (o >> 4) & 15; srcoff = (s ^ (row & 15)) * 4; }
    else               { row = o >> 7; const int s = (o >> 4) & 7;  srcoff = (s ^ (row & 7)) * 8;  }
    aseg[r] = oseg;
    asrc[r] = Am + ((long long)(bm + row) * p.lda + srcoff) * EA;
  }
  const char* bsrc[SEGB]; int bseg[SEGB];
  #pragma unroll
  for (int r = 0; r < SEGB; ++r) {
    const int oseg = (wid * SEGB + r) * 1024;
    const int o = oseg + lane * 16;
    int row, srcoff;
    if constexpr (BF32) { row = o >> 8; const int s = (o >> 4) & 15; srcoff = (s ^ (row & 15)) * 4; }
    else               { row = o >> 7; const int s = (o >> 4) & 7;  srcoff = (s ^ (row & 7)) * 8;  }
    bseg[r] = oseg;
    bsrc[r] = Bm + ((long long)(bn + row) * p.ldb + srcoff) * EB;
  }

  f32x4v acc[4][4];
  #pragma unroll
  for (int i = 0; i < 4; ++i)
    #pragma unroll
    for (int j = 0; j < 4; ++j) acc[i][j] = (f32x4v){0.f, 0.f, 0.f, 0.f};

  const int wr = wid >> 1, wc = wid & 1;
  const int fr_a = wr * 64 + (lane & 15);
  const int fr_b = wc * 64 + (lane & 15);
  const int fch  = lane >> 4;

  const int nK = p.K / 64;
  for (int kt = 0; kt < nK; ++kt) {
    #pragma unroll
    for (int r = 0; r < SEGA; ++r) { gload_lds16(asrc[r], smem + aseg[r]); asrc[r] += 64 * EA; }
    #pragma unroll
    for (int r = 0; r < SEGB; ++r) { gload_lds16(bsrc[r], smem + ABYTES + bseg[r]); bsrc[r] += 64 * EB; }
    __syncthreads();
    #pragma unroll
    for (int kk = 0; kk < 2; ++kk) {
      bf16x8v a[4], b[4];
      #pragma unroll
      for (int mi = 0; mi < 4; ++mi) {
        const int row = fr_a + mi * 16;
        if constexpr (AF32) {
          const int c2 = (fch + kk * 4) * 2;
          const f32x4v lo = *(const f32x4v*)(smem + row * 256 + ((c2 ^ (row & 15)) << 4));
          const f32x4v hi = *(const f32x4v*)(smem + row * 256 + (((c2 + 1) ^ (row & 15)) << 4));
          a[mi] = cvt8(lo, hi);
        } else {
          a[mi] = *(const bf16x8v*)(smem + row * 128 + (((fch + kk * 4) ^ (row & 7)) << 4));
        }
      }
      #pragma unroll
      for (int ni = 0; ni < 4; ++ni) {
        const int row = fr_b + ni * 16;
        if constexpr (BF32) {
          const int c2 = (fch + kk * 4) * 2;
          const f32x4v lo = *(const f32x4v*)(smem + ABYTES + row * 256 + ((c2 ^ (row & 15)) << 4));
          const f32x4v hi = *(const f32x4v*)(smem + ABYTES + row * 256 + (((c2 + 1) ^ (row & 15)) << 4));
          b[ni] = cvt8(lo, hi);
        } else {
          b[ni] = *(const bf16x8v*)(smem + ABYTES + row * 128 + (((fch + kk * 4) ^ (row & 7)) << 4));
        }
      }
      #pragma unroll
      for (int mi = 0; mi < 4; ++mi)
        #pragma unroll
        for (int ni = 0; ni < 4; ++ni)
          acc[mi][ni] = __builtin_amdgcn_mfma_f32_16x16x32_bf16(a[mi], b[ni], acc[mi][ni], 0, 0, 0);
    }
    __syncthreads();
  }

  const long long coff = (long long)i0*p.sC0 + (long long)i1*p.sC1 +
                         (long long)i2*p.sC2 + (long long)i3*p.sC3 +
                         (long long)blockIdx.z*p.zC;
  const int col0 = bn + wc * 64 + (lane & 15);
  const int row0 = bm + wr * 64 + ((lane >> 4) << 2);
  if (OUT_F32) {
    float* Cp = (float*)p.C + coff;
    #pragma unroll
    for (int mi = 0; mi < 4; ++mi)
      #pragma unroll
      for (int ni = 0; ni < 4; ++ni)
        #pragma unroll
        for (int j = 0; j < 4; ++j)
          Cp[(size_t)(row0 + mi*16 + j) * p.ldc + (col0 + ni*16)] = acc[mi][ni][j] * p.scale;
  } else {
    bf16* Cp = (bf16*)p.C + coff;
    #pragma unroll
    for (int mi = 0; mi < 4; ++mi)
      #pragma unroll
      for (int ni = 0; ni < 4; ++ni)
        #pragma unroll
        for (int j = 0; j < 4; ++j)
          Cp[(size_t)(row0 + mi*16 + j) * p.ldc + (col0 + ni*16)] =
              __float2bfloat16(acc[mi][ni][j] * p.scale);
  }
}

// ---------------------------------------------------------------------------
// 256x256-tile, 8-wave, PHASED double-buffered GEMM. R11 change: removed the
// sched_barrier(0) pair and the redundant lgkmcnt(0) asm from the phase body
// (m141: order-pinning defeats compiler pipelining, 510 vs 874 TF; m201's
// template has neither). Race-safety unchanged: 2 barriers/phase + counted
// vmcnt(4) (asm "memory" clobber fences cross-tile ds_read hoisting); every
// MFMA consumes its phase's reads, so values are in registers pre-barrier.
// ---------------------------------------------------------------------------
struct G256P {
  const bf16* A; const bf16* B; void* C;
  int lda, ldb, ldc, nt, tilesN, swz;
  int d0, d1, d2;
  long long sA0, sA1, sA2, sA3;
  long long sB0, sB1, sB2, sB3;
  long long sC0, sC1, sC2, sC3;
  long long zA, zB, zC;
  float scale;
};

template<int OUT_F32>
__global__ __launch_bounds__(512, 1)
void gemm256_bt(G256P p)
{
  __shared__ __attribute__((aligned(1024))) char smem[131072];
  const int tid = threadIdx.x, lane = tid & 63, wid = tid >> 6;

  int bx = blockIdx.x;
  if (p.swz) {
    const int nx = gridDim.x;
    const int q = nx >> 3, r = nx & 7;
    const int xcd = bx & 7, loc = bx >> 3;
    bx = (xcd < r ? xcd * (q + 1) : r * (q + 1) + (xcd - r) * q) + loc;
  }
  const int tn = bx % p.tilesN, tm = bx / p.tilesN;
  int idx = blockIdx.y;
  const int i0 = idx % p.d0; idx /= p.d0;
  const int i1 = idx % p.d1; idx /= p.d1;
  const int i2 = idx % p.d2;
  const int i3 = idx / p.d2;

  const bf16* Am = p.A + ((long long)i0*p.sA0 + (long long)i1*p.sA1 +
                          (long long)i2*p.sA2 + (long long)i3*p.sA3 +
                          (long long)blockIdx.z*p.zA) + (long long)tm * 256 * p.lda;
  const bf16* Bm = p.B + ((long long)i0*p.sB0 + (long long)i1*p.sB1 +
                          (long long)i2*p.sB2 + (long long)i3*p.sB3 +
                          (long long)blockIdx.z*p.zB) + (long long)tn * 256 * p.ldb;

  int arow[2][2]; int ach[2][2];
  #pragma unroll
  for (int hh = 0; hh < 2; ++hh)
    #pragma unroll
    for (int l = 0; l < 2; ++l) {
      const int seg = hh * 16 + wid * 2 + l;
      const int o = seg * 1024 + lane * 16;
      const int row = o >> 7;
      arow[hh][l] = row;
      ach[hh][l] = ((o >> 4) & 7) ^ (row & 7);
    }

  auto stageA = [&](int kt, int hh, int buf) {
    #pragma unroll
    for (int l = 0; l < 2; ++l) {
      const int seg = hh * 16 + wid * 2 + l;
      gload_lds16(Am + (long long)arow[hh][l] * p.lda + ach[hh][l] * 8 + kt * 64,
                  smem + buf * 32768 + seg * 1024);
    }
  };
  auto stageB = [&](int kt, int hh, int buf) {
    #pragma unroll
    for (int l = 0; l < 2; ++l) {
      const int seg = hh * 16 + wid * 2 + l;
      gload_lds16(Bm + (long long)arow[hh][l] * p.ldb + ach[hh][l] * 8 + kt * 64,
                  smem + 65536 + buf * 32768 + seg * 1024);
    }
  };

  stageA(0, 0, 0); stageA(0, 1, 0);
  stageB(0, 0, 0); stageB(0, 1, 0);
  if (p.nt > 1) { stageB(1, 0, 1); stageB(1, 1, 1); }
  asm volatile("s_waitcnt vmcnt(0)" ::: "memory");
  __builtin_amdgcn_s_barrier();

  f32x4v acc[8][4];
  #pragma unroll
  for (int i = 0; i < 8; ++i)
    #pragma unroll
    for (int j = 0; j < 4; ++j) acc[i][j] = (f32x4v){0.f, 0.f, 0.f, 0.f};

  const int wr = wid >> 2, wc = wid & 3;
  const int rA = wr * 128 + (lane & 15);
  const int rB = wc * 64 + (lane & 15);
  const int fch = lane >> 4;

  bf16x8v bfr[2][4];

  for (int t = 0; t < p.nt; ++t) {
    const int pb = t & 1;
    const char* Ab = smem + pb * 32768;
    const char* Bb = smem + 65536 + pb * 32768;

    #pragma unroll
    for (int q = 0; q < 4; ++q) {
      if (q == 0) {
        #pragma unroll
        for (int kk = 0; kk < 2; ++kk)
          #pragma unroll
          for (int ni = 0; ni < 4; ++ni) {
            const int row = rB + ni * 16;
            bfr[kk][ni] = *(const bf16x8v*)(Bb + row * 128 +
                                            (((fch + kk * 4) ^ (row & 7)) << 4));
          }
      }
      bf16x8v afr[2][2];
      #pragma unroll
      for (int kk = 0; kk < 2; ++kk)
        #pragma unroll
        for (int s = 0; s < 2; ++s) {
          const int row = rA + (q * 2 + s) * 16;
          afr[kk][s] = *(const bf16x8v*)(Ab + row * 128 +
                                         (((fch + kk * 4) ^ (row & 7)) << 4));
        }
      if (q == 0 && t + 1 < p.nt) stageA(t + 1, 0, pb ^ 1);
      if (q == 1 && t + 1 < p.nt) stageA(t + 1, 1, pb ^ 1);
      if (q == 2 && t + 2 < p.nt) stageB(t + 2, 0, pb);
      if (q == 3) {
        if (t + 2 < p.nt) {
          stageB(t + 2, 1, pb);
          asm volatile("s_waitcnt vmcnt(4)" ::: "memory");
        } else {
          asm volatile("s_waitcnt vmcnt(0)" ::: "memory");
        }
      }
      __builtin_amdgcn_s_barrier();
      __builtin_amdgcn_s_setprio(1);
      #pragma unroll
      for (int kk = 0; kk < 2; ++kk)
        #pragma unroll
        for (int s = 0; s < 2; ++s)
          #pragma unroll
          for (int ni = 0; ni < 4; ++ni)
            acc[q * 2 + s][ni] = __builtin_amdgcn_mfma_f32_16x16x32_bf16(
                afr[kk][s], bfr[kk][ni], acc[q * 2 + s][ni], 0, 0, 0);
      __builtin_amdgcn_s_setprio(0);
      __builtin_amdgcn_s_barrier();
    }
  }

  const long long coff = (long long)i0*p.sC0 + (long long)i1*p.sC1 +
                         (long long)i2*p.sC2 + (long long)i3*p.sC3 +
                         (long long)blockIdx.z*p.zC;
  const int col0 = tn * 256 + wc * 64 + (lane & 15);
  const int row0 = tm * 256 + wr * 128 + ((lane >> 4) << 2);
  if (OUT_F32) {
    float* Cp = (float*)p.C + coff;
    #pragma unroll
    for (int mi = 0; mi < 8; ++mi)
      #pragma unroll
      for (int ni = 0; ni < 4; ++ni)
        #pragma unroll
        for (int j = 0; j < 4; ++j)
          Cp[(size_t)(row0 + mi*16 + j) * p.ldc + (col0 + ni*16)] = acc[mi][ni][j] * p.scale;
  } else {
    bf16* Cp = (bf16*)p.C + coff;
    #pragma unroll
    for (int mi = 0; mi < 8; ++mi)
      #pragma unroll
      for (int ni = 0; ni < 4; ++ni)
        #pragma unroll
        for (int j = 0; j < 4; ++j)
          Cp[(size_t)(row0 + mi*16 + j) * p.ldc + (col0 + ni*16)] =
              __float2bfloat16(acc[mi][ni][j] * p.scale);
  }
}

// ---------------------------------------------------------------------------
// Fused K+V projection (shared X tile).
// ---------------------------------------------------------------------------
struct KVP {
  const float* X0; const float* X1;
  const bf16* Wk; const bf16* Wv;
  bf16* KT; bf16* Vc;
};

__global__ __launch_bounds__(256, 2)
void kv_fused(KVP p)
{
  __shared__ __attribute__((aligned(1024))) char smem[65536];
  const int tid = threadIdx.x, lane = tid & 63, wid = tid >> 6;
  const int jt = blockIdx.x & 1, nt = blockIdx.x >> 1;
  int idx = blockIdx.y;
  const int h = idx & 3; idx >>= 2;
  const int b = idx & 3; idx >>= 2;
  const int vi = idx;
  const float* X = (vi ? p.X1 : p.X0) + (size_t)b * 4194304 + (size_t)h * 256;
  const bf16* Wk = p.Wk + (size_t)h * 65536;
  const bf16* Wv = p.Wv + (size_t)h * 65536;
  const int n0 = nt * 128, j0 = jt * 128;

  const float* xsrc[8];
  #pragma unroll
  for (int r = 0; r < 8; ++r) {
    const int o = (wid * 8 + r) * 1024 + lane * 16;
    const int row = o >> 8, s = (o >> 4) & 15;
    xsrc[r] = X + (size_t)(n0 + row) * 1024 + (s ^ (row & 15)) * 4;
  }
  const bf16 *wksrc[4], *wvsrc[4];
  #pragma unroll
  for (int r = 0; r < 4; ++r) {
    const int o = (wid * 4 + r) * 1024 + lane * 16;
    const int row = o >> 7, s = (o >> 4) & 7;
    wksrc[r] = Wk + (size_t)(j0 + row) * 256 + (s ^ (row & 7)) * 8;
    wvsrc[r] = Wv + (size_t)(j0 + row) * 256 + (s ^ (row & 7)) * 8;
  }

  f32x4v accK[4][4], accV[4][4];
  #pragma unroll
  for (int i = 0; i < 4; ++i)
    #pragma unroll
    for (int j = 0; j < 4; ++j) {
      accK[i][j] = (f32x4v){0.f, 0.f, 0.f, 0.f};
      accV[i][j] = (f32x4v){0.f, 0.f, 0.f, 0.f};
    }

  const int wr = wid >> 1, wc = wid & 1;
  const int frW = wr * 64 + (lane & 15);
  const int frX = wc * 64 + (lane & 15);
  const int fch = lane >> 4;

  for (int kt = 0; kt < 4; ++kt) {
    #pragma unroll
    for (int r = 0; r < 8; ++r) { gload_lds16(xsrc[r], smem + (wid * 8 + r) * 1024); xsrc[r] += 64; }
    #pragma unroll
    for (int r = 0; r < 4; ++r) {
      gload_lds16(wksrc[r], smem + 32768 + (wid * 4 + r) * 1024); wksrc[r] += 64;
      gload_lds16(wvsrc[r], smem + 49152 + (wid * 4 + r) * 1024); wvsrc[r] += 64;
    }
    __syncthreads();
    #pragma unroll
    for (int kk = 0; kk < 2; ++kk) {
      bf16x8v wk[4], wv[4], x[4];
      #pragma unroll
      for (int mi = 0; mi < 4; ++mi) {
        const int row = frW + mi * 16;
        const int byo = row * 128 + (((fch + kk * 4) ^ (row & 7)) << 4);
        wk[mi] = *(const bf16x8v*)(smem + 32768 + byo);
        wv[mi] = *(const bf16x8v*)(smem + 49152 + byo);
      }
      #pragma unroll
      for (int ni = 0; ni < 4; ++ni) {
        const int row = frX + ni * 16;
        const int c2 = (fch + kk * 4) * 2;
        const f32x4v lo = *(const f32x4v*)(smem + row * 256 + ((c2 ^ (row & 15)) << 4));
        const f32x4v hi = *(const f32x4v*)(smem + row * 256 + (((c2 + 1) ^ (row & 15)) << 4));
        x[ni] = cvt8(lo, hi);
      }
      #pragma unroll
      for (int mi = 0; mi < 4; ++mi)
        #pragma unroll
        for (int ni = 0; ni < 4; ++ni) {
          accK[mi][ni] = __builtin_amdgcn_mfma_f32_16x16x32_bf16(wk[mi], x[ni], accK[mi][ni], 0, 0, 0);
          accV[ni][mi] = __builtin_amdgcn_mfma_f32_16x16x32_bf16(x[ni], wv[mi], accV[ni][mi], 0, 0, 0);
        }
    }
    __syncthreads();
  }

  const size_t kbase = (size_t)vi * 16777216 + (size_t)b * 4194304 + (size_t)h * 1048576;
  const size_t vbase = (size_t)vi * 16777216 + (size_t)b * 4194304;
  bf16* Kp = p.KT + kbase;
  bf16* Vp = p.Vc + vbase;
  const int rW = ((lane >> 4) << 2);
  #pragma unroll
  for (int mi = 0; mi < 4; ++mi)
    #pragma unroll
    for (int ni = 0; ni < 4; ++ni)
      #pragma unroll
      for (int j = 0; j < 4; ++j) {
        const int jrow = j0 + wr * 64 + mi * 16 + rW + j;
        const int ncol = n0 + wc * 64 + ni * 16 + (lane & 15);
        Kp[(size_t)jrow * 4096 + ncol] = __float2bfloat16(accK[mi][ni][j]);
        const int nrow = n0 + wc * 64 + ni * 16 + rW + j;
        const int jcol = j0 + wr * 64 + mi * 16 + (lane & 15);
        Vp[(size_t)nrow * 1024 + h * 256 + jcol] = __float2bfloat16(accV[ni][mi][j]);
      }
}

// ---------------------------------------------------------------------------
// weight conversions
// ---------------------------------------------------------------------------
__global__ void cvt3_f32_bf16(const float* __restrict__ a0, const float* __restrict__ a1,
                              const float* __restrict__ a2,
                              unsigned short* __restrict__ out, long long ostride, int n4) {
  const int i = blockIdx.x * 256 + threadIdx.x;
  if (i >= n4) return;
  const float* src = (blockIdx.y == 0) ? a0 : (blockIdx.y == 1) ? a1 : a2;
  const float4 v = ((const float4*)src)[i];
  ushort4 o;
  o.x = f2bu(v.x); o.y = f2bu(v.y); o.z = f2bu(v.z); o.w = f2bu(v.w);
  ((ushort4*)(out + (size_t)blockIdx.y * ostride))[i] = o;
}

__global__ void wpre_kernel(const float* __restrict__ Wout, const float* __restrict__ Woutd,
                            bf16* __restrict__ Wpre) {
  const int w = blockIdx.y;
  const int flat = blockIdx.x * 256 + threadIdx.x;
  const float* Wsrc = w ? Woutd : Wout;
  const int o  = flat >> 10;
  const int c2 = flat & 1023;
  const int h  = c2 >> 8;
  const int i  = c2 & 255;
  Wpre[(size_t)w * 1048576 + flat] = __float2bfloat16(Wsrc[o * 1024 + i * 4 + h]);
}

// ---------------------------------------------------------------------------
// Stage 1: per quarter-matrix sum/sumsq of z-summed scores (bf16 partials).
// ---------------------------------------------------------------------------
__global__ __launch_bounds__(256)
void stats_quarter(const bf16* __restrict__ sp, float* __restrict__ st) {
  const int m = blockIdx.x >> 2, q = blockIdx.x & 3;
  const size_t PS = 4194304;
  const bf16* s = sp + (size_t)m * 65536 + (size_t)q * 16384;
  const int tid = threadIdx.x, lane = tid & 63, w = tid >> 6;

  float sum = 0.f, sq = 0.f;
  for (int i = tid; i < 2048; i += 256) {
    const bf16x8v a = ((const bf16x8v*)s)[i];
    const bf16x8v b = ((const bf16x8v*)(s + PS))[i];
    const bf16x8v c = ((const bf16x8v*)(s + 2 * PS))[i];
    const bf16x8v d = ((const bf16x8v*)(s + 3 * PS))[i];
    #pragma unroll
    for (int e = 0; e < 8; ++e) {
      const float x = (b2f(a[e]) + b2f(b[e])) + (b2f(c[e]) + b2f(d[e]));
      sum += x;
      sq  += x * x;
    }
  }
  #pragma unroll
  for (int o = 32; o; o >>= 1) { sum += __shfl_xor(sum, o); sq += __shfl_xor(sq, o); }
  __shared__ float red[8];
  if (lane == 0) { red[w] = sum; red[4 + w] = sq; }
  __syncthreads();
  if (tid == 0) {
    st[blockIdx.x * 2]     = (red[0] + red[1]) + (red[2] + red[3]);
    st[blockIdx.x * 2 + 1] = (red[4] + red[5]) + (red[6] + red[7]);
  }
}

// ---------------------------------------------------------------------------
// Stage 2: combine quarter-stats; softmax over j per column i (bf16 partials).
// ---------------------------------------------------------------------------
__global__ __launch_bounds__(256)
void softmax_t(const bf16* __restrict__ sp, const float* __restrict__ st,
               bf16* __restrict__ pr) {
  const int m = blockIdx.x >> 2, iq = blockIdx.x & 3;
  const size_t PS = 4194304;
  const float sum = (st[m*8+0] + st[m*8+2]) + (st[m*8+4] + st[m*8+6]);
  const float sq  = (st[m*8+1] + st[m*8+3]) + (st[m*8+5] + st[m*8+7]);
  const float mean = sum * (1.f / 65536.f);
  const float var  = sq * (1.f / 65536.f) - mean * mean;
  const float inv  = rsqrtf(var + 1e-5f);

  const int tid = threadIdx.x;
  const int i  = iq * 64 + (tid & 63);
  const int jq = tid >> 6;
  const bf16* cb = sp + (size_t)m * 65536 + i;

  float e[64];
  float se = 0.f;
  #pragma unroll
  for (int jj = 0; jj < 64; ++jj) {
    const size_t o = (size_t)(jq * 64 + jj) * 256;
    const float v = (__bfloat162float(cb[o]) + __bfloat162float(cb[PS + o])) +
                    (__bfloat162float(cb[2 * PS + o]) + __bfloat162float(cb[3 * PS + o]));
    e[jj] = __expf((v - mean) * inv);
    se += e[jj];
  }
  __shared__ float seb[256];
  seb[tid] = se;
  __syncthreads();
  const int c = tid & 63;
  const float rvs = 1.f / ((seb[c] + seb[c + 64]) + (seb[c + 128] + seb[c + 192]));
  bf16* pc = pr + (size_t)m * 65536 + i;
  #pragma unroll
  for (int jj = 0; jj < 64; ++jj)
    pc[(size_t)(jq * 64 + jj) * 256] = __float2bfloat16(e[jj] * rvs);
}

// ---------------------------------------------------------------------------
// Host orchestration
// ---------------------------------------------------------------------------
extern "C" void kernel_launch(void* const* d_in, const int* in_sizes, int n_in,
                              void* d_out, int out_size, void* d_ws, size_t ws_size,
                              hipStream_t stream)
{
  const float* S     = (const float*)d_in[0];
  const float* SKV   = (const float*)d_in[1];
  const float* T     = (const float*)d_in[2];
  const float* TKV   = (const float*)d_in[3];
  const float* Wq    = (const float*)d_in[4];
  const float* Wk    = (const float*)d_in[5];
  const float* Wv    = (const float*)d_in[6];
  const float* Wout  = (const float*)d_in[7];
  const float* Woutd = (const float*)d_in[8];
  float* out = (float*)d_out;

  const int Hd = 4, Dd = 256;
  const long long NC  = 4096ll * 1024;
  const long long BNC = 4 * NC;
  const long long HDN = 1048576;

  char* ws = (char*)d_ws;
  size_t off = 0;
  auto alloc = [&](size_t bytes) -> void* {
    void* pp = ws + off; off += (bytes + 255) & ~(size_t)255; return pp;
  };
  bf16*  Wqb    = (bf16*)alloc((size_t)Hd * Dd * Dd * 2);
  bf16*  Wkb    = (bf16*)alloc((size_t)Hd * Dd * Dd * 2);
  bf16*  Wvb    = (bf16*)alloc((size_t)Hd * Dd * Dd * 2);
  bf16*  Wpre   = (bf16*)alloc(2ull * 1024 * 1024 * 2);
  bf16*  QT     = (bf16*)alloc(2 * BNC * 2);          // [qi][b][h][i][n]
  bf16*  KT     = (bf16*)alloc(2 * BNC * 2);          // [ki][b][h][j][n]
  bf16*  Vc     = (bf16*)alloc(2 * BNC * 2);          // [vi][b][n][h*256+j]
  bf16*  sparts = (bf16*)alloc(4ull * 4194304 * 2);   // 4 split-K partials (bf16)
  float* stats  = (float*)alloc(256ull * 2 * 4);
  bf16*  probsT = (bf16*)alloc(64ull * 65536 * 2);    // [pp][b][h][j][i]
  bf16*  Weff   = QT;  // reuse: QT dead after scores GEMM; [b][ki][qi][o][c]
  if (ws_size < off) return;

  // 1) weight conversions
  {
    const int w4 = (Hd * Dd * Dd) / 4;
    cvt3_f32_bf16<<<dim3((w4 + 255) / 256, 3), dim3(256), 0, stream>>>(
        Wq, Wk, Wv, (unsigned short*)Wqb, (long long)Hd * Dd * Dd, w4);
    wpre_kernel<<<dim3(4096, 2), dim3(256), 0, stream>>>(Wout, Woutd, Wpre);
  }

  GemmP g{};

  // 2) Q projection
  g.A = Wqb; g.B = S; g.A2 = nullptr; g.B2 = T; g.C = QT;
  g.K = 256; g.lda = 256; g.ldb = 1024; g.ldc = 4096; g.tilesN = 32; g.swz = 0;
  g.d0 = 4; g.d1 = 4; g.d2 = 2;
  g.sA0 = 65536; g.sA1 = 0;  g.sA2 = 0;   g.sA3 = 0;
  g.sB0 = 256;   g.sB1 = NC; g.sB2 = 0;   g.sB3 = 0;
  g.sC0 = HDN;   g.sC1 = NC; g.sC2 = BNC; g.sC3 = 0;
  g.zA = 0; g.zB = 0; g.zC = 0;
  g.scale = 1.f;
  gemm_bt<0, 0, 1><<<dim3(2 * 32, 32), dim3(256), 0, stream>>>(g);

  // 3) fused K+V projection
  {
    KVP kv{SKV, TKV, Wkb, Wvb, KT, Vc};
    kv_fused<<<dim3(64, 32), dim3(256), 0, stream>>>(kv);
  }

  // 4) scores split-K=4 on the phased 256-tile kernel; bf16 partials.
  G256P h{};
  h.A = KT; h.B = QT; h.C = sparts;
  h.lda = 4096; h.ldb = 4096; h.ldc = 256; h.nt = 16; h.tilesN = 1; h.swz = 0;
  h.d0 = 4; h.d1 = 4; h.d2 = 2;                       // (h, b, ki, qi)
  h.sA0 = HDN;   h.sA1 = NC;     h.sA2 = BNC;     h.sA3 = 0;
  h.sB0 = HDN;   h.sB1 = NC;     h.sB2 = 0;       h.sB3 = BNC;
  h.sC0 = 65536; h.sC1 = 262144; h.sC2 = 1048576; h.sC3 = 2097152;
  h.zA = 1024; h.zB = 1024; h.zC = 4194304;
  h.scale = 0.03125f;
  gemm256_bt<0><<<dim3(1, 64, 4), dim3(512), 0, stream>>>(h);

  // 5) stats + softmax (read bf16 partials)
  stats_quarter<<<dim3(256), dim3(256), 0, stream>>>(sparts, stats);
  softmax_t<<<dim3(256), dim3(256), 0, stream>>>(sparts, stats, probsT);

  // 6) Weff[b][ki][qi][o][h*256+j] = sum_i Wpre[qi][o][h*256+i] * probsT[2qi+ki][b][h][j][i]
  g.A = Wpre; g.B = probsT; g.A2 = nullptr; g.B2 = nullptr; g.C = Weff;
  g.K = 256; g.lda = 1024; g.ldb = 256; g.ldc = 1024; g.tilesN = 2; g.swz = 0;
  g.d0 = 4; g.d1 = 4; g.d2 = 2;                       // (h, b, ki, qi)
  g.sA0 = 256;   g.sA1 = 0;       g.sA2 = 0;       g.sA3 = 1048576;
  g.sB0 = 65536; g.sB1 = 262144;  g.sB2 = 1048576; g.sB3 = 2097152;
  g.sC0 = 256;   g.sC1 = 4194304; g.sC2 = 2097152; g.sC3 = 1048576;
  g.zA = 0; g.zB = 0; g.zC = 0;
  g.scale = 1.f;
  gemm_bt<0, 0, 0><<<dim3(8 * 2, 64), dim3(256), 0, stream>>>(g);

  // 7) final on the CLEANED phased 256-tile kernel:
  //    out[qi+2ki][b][n][o] = sum_c Vc[ki][b][n][c] * Weff[b][ki][qi][o][c]
  h.A = Vc; h.B = Weff; h.C = out;
  h.lda = 1024; h.ldb = 1024; h.ldc = 1024; h.nt = 16; h.tilesN = 4; h.swz = 1;
  h.d0 = 2; h.d1 = 4; h.d2 = 2;                       // (qi, b, ki)
  h.sA0 = 0;       h.sA1 = NC;      h.sA2 = BNC;     h.sA3 = 0;
  h.sB0 = 1048576; h.sB1 = 4194304; h.sB2 = 2097152; h.sB3 = 0;
  h.sC0 = BNC;     h.sC1 = NC;      h.sC2 = 2 * BNC; h.sC3 = 0;
  h.zA = 0; h.zB = 0; h.zC = 0;
  h.scale = 1.f;
  gemm256_bt<1><<<dim3(16 * 4, 16), dim3(512), 0, stream>>>(h);

  (void)in_sizes; (void)n_in; (void)out_size;
}